// Round 1
// baseline (288.426 us; speedup 1.0000x reference)
//
#include <hip/hip_runtime.h>
#include <hip/hip_bf16.h>
#include <math.h>

#define B_ROWS 8192
#define NEXP 16

typedef __attribute__((ext_vector_type(8))) short short8;
typedef __attribute__((ext_vector_type(4))) float f32x4;

__device__ __forceinline__ float softplus_f(float x) {
    return fmaxf(x, 0.f) + log1pf(expf(-fabsf(x)));
}

__device__ __forceinline__ float bf2f(short u) {
    union { unsigned int i; float f; } c;
    c.i = ((unsigned int)(unsigned short)u) << 16;
    return c.f;
}

__device__ __forceinline__ short f2bf_s(float x) {
    __hip_bfloat16 h = __float2bfloat16(x);
    return *(short*)&h;
}

__device__ __forceinline__ void gll16(const void* g, void* l) {
    __builtin_amdgcn_global_load_lds(
        (const __attribute__((address_space(1))) void*)g,
        (__attribute__((address_space(3))) void*)l, 16, 0, 0);
}

#define FENCE() asm volatile("" ::: "memory")

// ================= UBER PREP (all prep roles, ONE launch) ==================
// [0,8)          WgT GEMM from RAW f32 (FIRST: long pole overlaps the casts)
// [8,8200)       y cast
// [8200,9224)    Mt2 permute
// [9224,9736)    W1yt tcast
// [9736,9768)    W1m2 zero-padded tcast
// [9768,10024)   W0p prep
// [10024,10056)  l0wyt tcast
// 10056          biasfold + acc/counter zero
// [10057,10074)  W2 swizzle preps
__device__ void cast_body(const float* in, __hip_bfloat16* out, int blk, int tid) {
    int i = blk * 256 + tid;
    float4 v = ((const float4*)in)[i];
    union { ushort4 u; __hip_bfloat16 h[4]; } p;
    p.h[0] = __float2bfloat16(v.x);
    p.h[1] = __float2bfloat16(v.y);
    p.h[2] = __float2bfloat16(v.z);
    p.h[3] = __float2bfloat16(v.w);
    ((ushort4*)out)[i] = p.u;
}

__global__ __launch_bounds__(256) void prep_all(
    const float* __restrict__ y, const float* __restrict__ M,
    const float* __restrict__ lW1, const float* __restrict__ gw0,
    const float* __restrict__ l0w, const float* __restrict__ gb1,
    const float* __restrict__ l0b, const float* __restrict__ lW2,
    const float* __restrict__ l1w, const float* __restrict__ gw1,
    __hip_bfloat16* __restrict__ yb, short* __restrict__ Mt2,
    __hip_bfloat16* __restrict__ W1yt, short* __restrict__ W1m2,
    __hip_bfloat16* __restrict__ W0p, __hip_bfloat16* __restrict__ l0wyt,
    float* __restrict__ bing, short* __restrict__ W2sb,
    short* __restrict__ L1ws, __hip_bfloat16* __restrict__ WgTb,
    double* __restrict__ acc, int* __restrict__ counter)
{
    __shared__ __align__(16) char smem[66048];
    const int b = blockIdx.x;
    const int tid = threadIdx.x;
    const int lane = tid & 63, w = tid >> 6;

    if (b < 8) {
        // ---- WgT[c][j] = sum_o l0w[(1024+o)*128+c]*gw1[j*1024+o], raw f32 ----
        short* As = (short*)smem;
        short* Bs = (short*)(smem + 16384);
        const int bn = b * 128;
        const int wr = w >> 1, wc = w & 1;
        const int l15 = lane & 15, l4 = lane >> 4;

        f32x4 acc4[4][4] = {};
        for (int k0 = 0; k0 < 1024; k0 += 64) {
            {   // stage A: transpose-cast into swizzled image
                int c4 = (tid & 31) * 4;
                int kkr0 = tid >> 5;
                #pragma unroll
                for (int r = 0; r < 8; ++r) {
                    int kk = r * 8 + kkr0;
                    float4 v = *(const float4*)&l0w[(long)(1024 + k0 + kk) * 128 + c4];
                    int g = kk >> 3, sub = kk & 7;
                    #pragma unroll
                    for (int i = 0; i < 4; ++i) {
                        int row = c4 + i;
                        As[row * 64 + (g ^ (row & 7)) * 8 + sub] = f2bf_s(((const float*)&v)[i]);
                    }
                }
            }
            {   // stage B: row-cast into swizzled image
                int jr0 = tid >> 3;
                int g = tid & 7;
                #pragma unroll
                for (int s = 0; s < 4; ++s) {
                    int jrel = s * 32 + jr0;
                    const float* src = &gw1[(long)(bn + jrel) * 1024 + k0 + g * 8];
                    float4 v0 = *(const float4*)src;
                    float4 v1 = *(const float4*)(src + 4);
                    union { short8 v; short sh[8]; } o;
                    o.sh[0] = f2bf_s(v0.x); o.sh[1] = f2bf_s(v0.y);
                    o.sh[2] = f2bf_s(v0.z); o.sh[3] = f2bf_s(v0.w);
                    o.sh[4] = f2bf_s(v1.x); o.sh[5] = f2bf_s(v1.y);
                    o.sh[6] = f2bf_s(v1.z); o.sh[7] = f2bf_s(v1.w);
                    *(short8*)&Bs[jrel * 64 + (g ^ (jrel & 7)) * 8] = o.v;
                }
            }
            __syncthreads();
            #pragma unroll
            for (int st = 0; st < 2; ++st) {
                const int gr = (st * 4 + l4) ^ (l15 & 7);
                short8 a[4], bv[4];
                #pragma unroll
                for (int m = 0; m < 4; ++m)
                    a[m] = *(const short8*)&As[(wr * 64 + m * 16 + l15) * 64 + gr * 8];
                #pragma unroll
                for (int n = 0; n < 4; ++n)
                    bv[n] = *(const short8*)&Bs[(wc * 64 + n * 16 + l15) * 64 + gr * 8];
                #pragma unroll
                for (int m = 0; m < 4; ++m)
                    #pragma unroll
                    for (int n = 0; n < 4; ++n)
                        acc4[m][n] = __builtin_amdgcn_mfma_f32_16x16x32_bf16(a[m], bv[n], acc4[m][n], 0, 0, 0);
            }
            __syncthreads();
        }
        #pragma unroll
        for (int m = 0; m < 4; ++m) {
            int row = wr * 64 + m * 16 + l4 * 4;
            #pragma unroll
            for (int n = 0; n < 4; ++n) {
                int col = bn + wc * 64 + n * 16 + l15;
                #pragma unroll
                for (int r = 0; r < 4; ++r)
                    WgTb[(long)(row + r) * 1024 + col] = __float2bfloat16(acc4[m][n][r]);
            }
        }
        return;
    }

    if (b < 8200) { cast_body(y, yb, b - 8, tid); return; }

    if (b < 9224) {
        // ---- Mt2 permute ----
        short* t = (short*)smem;
        const long r0 = (long)(b - 8200) * 8;
        #pragma unroll
        for (int i = 0; i < 8; ++i) {
            int idx = i * 1024 + tid * 4;
            float4 v = *(const float4*)&M[r0 * 1024 + idx];
            short4 s;
            s.x = f2bf_s(v.x); s.y = f2bf_s(v.y); s.z = f2bf_s(v.z); s.w = f2bf_s(v.w);
            *(short4*)&t[idx] = s;
        }
        __syncthreads();
        const int e = tid & 15, rr = (tid >> 4) & 7, hf = tid >> 7;
        #pragma unroll
        for (int c = 0; c < 4; ++c) {
            union { short8 v; short s[8]; } o;
            #pragma unroll
            for (int j = 0; j < 8; ++j)
                o.s[j] = t[rr * 1024 + (hf * 32 + c * 8 + j) * 16 + e];
            *(short8*)&Mt2[(long)(e >> 1) * (8192L * 128) + (r0 + rr) * 128
                           + (e & 1) * 64 + hf * 32 + c * 8] = o.v;
        }
        return;
    }

    float (*t)[129] = (float(*)[129])smem;

    if (b < 9736) {
        int l = b - 9224, bx = l & 15, by = l >> 4;
        int n0 = bx * 128, k0 = by * 32;
        long base = 64L * 128 + (long)bx * (1088L * 128);
        #pragma unroll
        for (int ll = 0; ll < 16; ++ll) {
            int idx = tid + ll * 256;
            int kk = idx >> 7, nn = idx & 127;
            t[kk][nn] = lW1[base + (long)(k0 + kk) * 128 + nn];
        }
        __syncthreads();
        int nn = tid >> 1, kb = (tid & 1) * 16;
        #pragma unroll
        for (int j = 0; j < 16; ++j)
            W1yt[(long)(n0 + nn) * 1024 + k0 + kb + j] = __float2bfloat16(t[kb + j][nn]);
        return;
    }

    if (b < 9768) {
        int l = b - 9736, bx = l & 15, by = l >> 4;
        int n0 = bx * 128, k0 = by * 32;
        long base = (long)bx * (1088L * 128);
        #pragma unroll
        for (int ll = 0; ll < 16; ++ll) {
            int idx = tid + ll * 256;
            int kk = idx >> 7, nn = idx & 127;
            if (kk < 32) t[kk][nn] = lW1[base + (long)(k0 + kk) * 128 + nn];
        }
        __syncthreads();
        int nn = tid >> 1, kb = (tid & 1) * 16;
        int half = bx & 1;
        #pragma unroll
        for (int j = 0; j < 16; ++j) {
            W1m2[(long)(n0 + nn) * 128 + half * 64 + k0 + kb + j] = f2bf_s(t[kb + j][nn]);
            W1m2[(long)(n0 + nn) * 128 + (1 - half) * 64 + k0 + kb + j] = 0;
        }
        return;
    }

    if (b < 10024) {
        int l = b - 9768, bx = l & 7, by = l >> 3;
        int n0 = bx * 128, k0 = by * 32;
        int e = k0 >> 6, dd0 = k0 & 63;
        #pragma unroll
        for (int ll = 0; ll < 16; ++ll) {
            int idx = tid + ll * 256;
            int kk = idx >> 7, nn = idx & 127;
            t[kk][nn] = gw0[(long)((dd0 + kk) * 16 + e) * 1024 + n0 + nn];
        }
        __syncthreads();
        int nn = tid >> 1, kb = (tid & 1) * 16;
        #pragma unroll
        for (int j = 0; j < 16; ++j)
            W0p[(long)(n0 + nn) * 1024 + k0 + kb + j] = __float2bfloat16(t[kb + j][nn]);
        return;
    }

    if (b < 10056) {
        int by = b - 10024;
        int k0 = by * 32;
        #pragma unroll
        for (int ll = 0; ll < 16; ++ll) {
            int idx = tid + ll * 256;
            int kk = idx >> 7, nn = idx & 127;
            t[kk][nn] = l0w[(long)(k0 + kk) * 128 + nn];
        }
        __syncthreads();
        int nn = tid >> 1, kb = (tid & 1) * 16;
        #pragma unroll
        for (int j = 0; j < 16; ++j)
            l0wyt[(long)nn * 1024 + k0 + kb + j] = __float2bfloat16(t[kb + j][nn]);
        return;
    }

    if (b == 10056) {
        if (tid < 128) {
            float s = l0b[tid];
            for (int o = 0; o < 1024; ++o)
                s = fmaf(gb1[o], l0w[(1024 + o) * 128 + tid], s);
            bing[tid] = s;
        }
        if (tid == 255) { acc[0] = 0.0; acc[1] = 0.0; *counter = 0; }
        return;
    }

    {
        int bb = b - 10057;
        const float* in = (bb < 16) ? lW2 + (long)bb * 16384 : l1w;
        short* out = (bb < 16) ? W2sb + (long)bb * 16384 : L1ws;
        #pragma unroll
        for (int l = 0; l < 64; ++l) {
            int idx = l * 256 + tid;
            t[idx >> 7][idx & 127] = in[idx];
        }
        __syncthreads();
        #pragma unroll
        for (int l = 0; l < 8; ++l) {
            int c = l * 256 + tid;
            int col = c >> 4, kc = c & 15;
            int kcs = kc ^ (col & 7);
            union { short8 v; short s[8]; } u;
            #pragma unroll
            for (int j = 0; j < 8; ++j)
                u.s[j] = f2bf_s(t[kc * 8 + j][col]);
            *(short8*)&out[col * 128 + kcs * 8] = u.v;
        }
    }
}

// ================= GEMM8: counted-vmcnt pipelined mega GEMM ================
// BM=256 x BN=128, BK=64, 512 thr / 8 waves (4M x 2N, per-wave 64x64).
// 2 phases per K-tile; each phase: {8 ds_read_b128 + 3 global_load_lds +
// raw s_barrier + setprio(1) 16xMFMA setprio(0) + counted vmcnt + barrier}.
// vmcnt NEVER drains to 0 in the main loop (T3+T4); 6->3->0 in epilogue.
// LDS [slot][khalf]: A=[4 kc][256 rows][16B], B=[4 kc][128 rows][16B] = 96 KB,
// conflict-free by construction (8-lane groups read 128B contiguous).
// Tile counts: grp0=512, grp2=256, grp3=32 (heavy, K=1024) = 800 ~ 3.125
// rounds of 256 CUs; grp1's 512 cheap K=128 tiles pack the fractional tail.
__global__ __launch_bounds__(512, 2) void gemm8(
    const short* __restrict__ yb, const short* __restrict__ W1yt,
    __hip_bfloat16* __restrict__ Y1b,
    const short* __restrict__ Mt2, const short* __restrict__ W1m2,
    __hip_bfloat16* __restrict__ Mpb,
    const short* __restrict__ W0p, const float* __restrict__ gb0,
    __hip_bfloat16* __restrict__ H0b,
    const short* __restrict__ l0wyt, __hip_bfloat16* __restrict__ Tyb)
{
    __shared__ __align__(16) char smem[98304];
    const int tid = threadIdx.x;
    const int lane = tid & 63, w = tid >> 6;
    const int l15 = lane & 15, l4 = lane >> 4;
    const int bid = blockIdx.x;

    int grp, bm, bn, K;
    const short* A; const short* Wt; __hip_bfloat16* C; int ldc;
    if (bid < 512) {
        grp = 0; const int nc = bid & 15, mt = bid >> 4;
        bm = mt * 256; bn = nc * 128;
        A = yb; Wt = W1yt + (long)bn * 1024; K = 1024; C = Y1b; ldc = 2048;
    } else if (bid < 768) {
        grp = 2; const int i = bid - 512; const int nc = i & 7, mt = i >> 3;
        bm = mt * 256; bn = nc * 128;
        A = Mt2; Wt = W0p + (long)bn * 1024; K = 1024; C = H0b; ldc = 1024;
    } else if (bid < 800) {
        grp = 3; bm = (bid - 768) * 256; bn = 0;
        A = yb; Wt = l0wyt; K = 1024; C = Tyb; ldc = 128;
    } else {
        grp = 1; const int i = bid - 800; const int nc = i & 15, mt = i >> 4;
        bm = mt * 256; bn = nc * 128;
        A = Mt2 + (long)(nc >> 1) * (8192L * 128);
        Wt = W1m2 + (long)bn * 128; K = 128; C = Mpb; ldc = 2048;
    }
    const int nt = K >> 6;

    // staging maps (wave-uniform LDS bases; per-lane global sources)
    const int aRow = tid & 255;          // = (w&3)*64 + lane
    const int aKc0 = tid >> 8;           // kc = 2r + aKc0
    const int bRow = tid & 127;          // = (w&1)*64 + lane
    const int bKc  = tid >> 7;           // = w>>1
    const int aDst0 = (aRow & 192) * 16; // row-block byte offset
    const int bDst0 = (bRow & 64) * 16;

    auto STAGE = [&](int t, int kh) {
        const int slot = t & 1;
        const int koff = t * 64 + kh * 32;
        char* Ab = smem + slot * 32768 + kh * 16384;
        char* Bb = smem + 65536 + slot * 16384 + kh * 8192;
        #pragma unroll
        for (int r = 0; r < 2; ++r) {
            const int kc = r * 2 + aKc0;
            const short* src;
            if (grp == 2) {
                const int g = (koff >> 3) + kc;
                src = A + (long)(g >> 4) * (8192L * 128)
                        + (long)(bm + aRow) * 128 + (g & 15) * 8;
            } else {
                src = A + (long)(bm + aRow) * K + koff + kc * 8;
            }
            gll16(src, Ab + kc * 4096 + aDst0);
        }
        gll16(Wt + (long)bRow * K + koff + bKc * 8, Bb + bKc * 2048 + bDst0);
    };

    f32x4 acc[4][4] = {};
    const int aoff = l4 * 4096 + ((w >> 1) * 64 + l15) * 16;
    const int boff = l4 * 2048 + ((w & 1) * 64 + l15) * 16;

    // stageSel: 0 -> stage (t+1, k1); 1 -> stage (t+2, k0); -1 -> none
    auto PHASE = [&](int t, int kh, int stageSel) {
        const int slot = t & 1;
        const char* Ab = smem + slot * 32768 + kh * 16384;
        const char* Bb = smem + 65536 + slot * 16384 + kh * 8192;
        short8 a[4], b[4];
        #pragma unroll
        for (int m = 0; m < 4; ++m) a[m] = *(const short8*)(Ab + aoff + m * 256);
        #pragma unroll
        for (int n = 0; n < 4; ++n) b[n] = *(const short8*)(Bb + boff + n * 256);
        if (stageSel == 0) STAGE(t + 1, 1);
        else if (stageSel == 1) STAGE(t + 2, 0);
        FENCE();
        __builtin_amdgcn_s_barrier();   // barrier 1: align reads/stage vs MFMA
        FENCE();
        __builtin_amdgcn_s_setprio(1);
        #pragma unroll
        for (int m = 0; m < 4; ++m)
            #pragma unroll
            for (int n = 0; n < 4; ++n)
                acc[m][n] = __builtin_amdgcn_mfma_f32_16x16x32_bf16(a[m], b[n], acc[m][n], 0, 0, 0);
        __builtin_amdgcn_s_setprio(0);
        FENCE();
    };

    // prologue: 3 half-regions = 9 loads; wait leaves 6 -> (0,k0) landed
    STAGE(0, 0); STAGE(0, 1); STAGE(1, 0);
    asm volatile("s_waitcnt vmcnt(6)" ::: "memory");
    __builtin_amdgcn_s_barrier();
    FENCE();

    for (int t = 0; t < nt - 2; ++t) {
        PHASE(t, 0, 0);
        asm volatile("s_waitcnt vmcnt(6)" ::: "memory");
        __builtin_amdgcn_s_barrier(); FENCE();
        PHASE(t, 1, 1);
        asm volatile("s_waitcnt vmcnt(6)" ::: "memory");
        __builtin_amdgcn_s_barrier(); FENCE();
    }
    PHASE(nt - 2, 0, 0);                       // stages (nt-1, k1)
    asm volatile("s_waitcnt vmcnt(6)" ::: "memory");
    __builtin_amdgcn_s_barrier(); FENCE();
    PHASE(nt - 2, 1, -1);
    asm volatile("s_waitcnt vmcnt(3)" ::: "memory");
    __builtin_amdgcn_s_barrier(); FENCE();
    PHASE(nt - 1, 0, -1);
    asm volatile("s_waitcnt vmcnt(0)" ::: "memory");
    __builtin_amdgcn_s_barrier(); FENCE();
    PHASE(nt - 1, 1, -1);

    #pragma unroll
    for (int m = 0; m < 4; ++m) {
        const int row = bm + (w >> 1) * 64 + m * 16 + l4 * 4;
        #pragma unroll
        for (int n = 0; n < 4; ++n) {
            const int col = bn + (w & 1) * 64 + n * 16 + l15;
            const float bv = (grp == 2) ? gb0[col] : 0.f;
            #pragma unroll
            for (int r = 0; r < 4; ++r) {
                float v = acc[m][n][r] + bv;
                if (grp == 2) v = fmaxf(v, 0.f);
                C[(long)(row + r) * ldc + col] = __float2bfloat16(v);
            }
        }
    }
}

// ===== tail_plus: [0,2048) local tail (XCD-swz), [2048,2112) Tg GEMM,
//                  [2112,2176) Ty GEMM (moved out of the mega GEMM) ========
__global__ __launch_bounds__(256) void tail_plus(
    const __hip_bfloat16* __restrict__ Yp, const __hip_bfloat16* __restrict__ Mq,
    const float* __restrict__ bin, const short* __restrict__ W2s,
    const float* __restrict__ b2, const float* __restrict__ w3,
    const float* __restrict__ b3, double* __restrict__ acc,
    const short* __restrict__ H0b, const short* __restrict__ WgTb,
    __hip_bfloat16* __restrict__ Tgb,
    const short* __restrict__ ybs, const short* __restrict__ l0ws,
    __hip_bfloat16* __restrict__ Tyb)
{
    __shared__ __align__(16) char smem[68096];
    const int bid = blockIdx.x;
    const int tid = threadIdx.x;
    const int lane = tid & 63;
    const int l15 = lane & 15, l4 = lane >> 4;

    if (bid >= 2048) {
        const int sel = bid - 2048;
        const short* Ain = (sel < 64) ? H0b : ybs;
        const short* Bin = (sel < 64) ? WgTb : l0ws;
        __hip_bfloat16* Co = (sel < 64) ? Tgb : Tyb;
        short* As = (short*)smem;
        short* Bs = (short*)(smem + 16384);
        const int w = tid >> 6;
        const int wr = w >> 1, wc = w & 1;
        const int bm = (sel & 63) * 128;
        const int srow = lane >> 3;
        const int gsrc = (lane & 7) ^ srow;

        f32x4 a4[4][4] = {};
        for (int k0 = 0; k0 < 1024; k0 += 64) {
            #pragma unroll
            for (int s = 0; s < 4; ++s) {
                const int rrel = s * 32 + w * 8 + srow;
                gll16(Ain + (long)(bm + rrel) * 1024 + k0 + gsrc * 8,
                      As + (s * 32 + w * 8) * 64);
                gll16(Bin + (long)rrel * 1024 + k0 + gsrc * 8,
                      Bs + (s * 32 + w * 8) * 64);
            }
            __syncthreads();
            #pragma unroll
            for (int st = 0; st < 2; ++st) {
                const int gr = (st * 4 + l4) ^ (l15 & 7);
                short8 a[4], b[4];
                #pragma unroll
                for (int m = 0; m < 4; ++m)
                    a[m] = *(const short8*)&As[(wr * 64 + m * 16 + l15) * 64 + gr * 8];
                #pragma unroll
                for (int n = 0; n < 4; ++n)
                    b[n] = *(const short8*)&Bs[(wc * 64 + n * 16 + l15) * 64 + gr * 8];
                #pragma unroll
                for (int m = 0; m < 4; ++m)
                    #pragma unroll
                    for (int n = 0; n < 4; ++n)
                        a4[m][n] = __builtin_amdgcn_mfma_f32_16x16x32_bf16(a[m], b[n], a4[m][n], 0, 0, 0);
            }
            __syncthreads();
        }
        #pragma unroll
        for (int m = 0; m < 4; ++m) {
            int row = bm + (w >> 1) * 64 + m * 16 + l4 * 4;
            #pragma unroll
            for (int n = 0; n < 4; ++n) {
                int col = (w & 1) * 64 + n * 16 + l15;
                #pragma unroll
                for (int r = 0; r < 4; ++r)
                    Co[(long)(row + r) * 128 + col] = __float2bfloat16(a4[m][n][r]);
            }
        }
        return;
    }

    const int wkid = (bid & 7) * 256 + (bid >> 3);
    const int e = wkid & 15;
    const int b0 = (wkid >> 4) * 64;
    const int cbase = e * 128;
    const int wid = tid >> 6;
    const int side = wid >> 1;
    const int wr = wid & 1;
    const int widthIn = 2048;

    short* h1 = (short*)smem;
    short* Bs = (short*)(smem + 32768);
    float* bins = (float*)(smem + 65536);
    float* b2s  = (float*)(smem + 66048);
    float* w3s  = (float*)(smem + 66560);
    float* red  = (float*)(smem + 67072);

    const short* W2e = W2s + (long)e * 16384;
    #pragma unroll
    for (int l = 0; l < 8; ++l) {
        int cb = (l * 4 + wid) * 64;
        gll16(W2e + (long)(cb + lane) * 8, &Bs[cb * 8]);
    }
    if (tid < 128) {
        bins[tid] = bin[cbase + tid];
        b2s[tid]  = b2[cbase + tid];
        w3s[tid]  = w3[cbase + tid];
    }
    __syncthreads();

    const short* Ys = (const short*)Yp;
    const short* Ms = (const short*)Mq;
    #pragma unroll
    for (int c = 0; c < 4; ++c) {
        int chunk = c * 256 + tid;
        int row = chunk >> 4, kc = chunk & 15;
        short8 yv = *(const short8*)&Ys[(long)(b0 + row) * widthIn + cbase + kc * 8];
        float yf[8];
        #pragma unroll
        for (int j = 0; j < 8; ++j) yf[j] = bf2f(yv[j]) + bins[kc * 8 + j];
        int dst = row * 128 + (kc ^ (row & 7)) * 8;
        #pragma unroll
        for (int s = 0; s < 2; ++s) {
            int rowm = (b0 + row + s) & (B_ROWS - 1);
            short8 mv = *(const short8*)&Ms[(long)rowm * widthIn + cbase + kc * 8];
            union { short8 v; short sh[8]; } o;
            #pragma unroll
            for (int j = 0; j < 8; ++j)
                o.sh[j] = f2bf_s(fmaxf(yf[j] + bf2f(mv[j]), 0.f));
            *(short8*)&h1[s * 8192 + dst] = o.v;
        }
    }
    __syncthreads();

    f32x4 accv[2][8] = {};
    #pragma unroll
    for (int st = 0; st < 4; ++st) {
        short8 a[2], b[8];
        #pragma unroll
        for (int m = 0; m < 2; ++m) {
            int row = wr * 32 + m * 16 + l15;
            int ch = (st * 4 + l4) ^ (row & 7);
            a[m] = *(const short8*)&h1[side * 8192 + row * 128 + ch * 8];
        }
        #pragma unroll
        for (int n = 0; n < 8; ++n) {
            int col = n * 16 + l15;
            int ch = (st * 4 + l4) ^ (col & 7);
            b[n] = *(const short8*)&Bs[col * 128 + ch * 8];
        }
        #pragma unroll
        for (int m = 0; m < 2; ++m)
            #pragma unroll
            for (int n = 0; n < 8; ++n)
                accv[m][n] = __builtin_amdgcn_mfma_f32_16x16x32_bf16(a[m], b[n], accv[m][n], 0, 0, 0);
    }

    float p[2][4] = {};
    #pragma unroll
    for (int m = 0; m < 2; ++m)
        #pragma unroll
        for (int n = 0; n < 8; ++n) {
            int colL = n * 16 + l15;
            float bb = b2s[colL], ww = w3s[colL];
            #pragma unroll
            for (int r = 0; r < 4; ++r) {
                float h2 = fmaxf(accv[m][n][r] + bb, 0.f);
                p[m][r] = fmaf(h2, ww, p[m][r]);
            }
        }
    #pragma unroll
    for (int m = 0; m < 2; ++m)
        #pragma unroll
        for (int r = 0; r < 4; ++r)
            #pragma unroll
            for (int off = 1; off < 16; off <<= 1)
                p[m][r] += __shfl_xor(p[m][r], off, 64);

    float mysum = 0.f;
    if (l15 == 0) {
        float bb = b3[e];
        #pragma unroll
        for (int m = 0; m < 2; ++m)
            #pragma unroll
            for (int r = 0; r < 4; ++r) {
                float s = p[m][r] + bb;
                mysum += softplus_f(side ? s : -s);
            }
    }
    red[tid] = mysum;
    __syncthreads();
    for (int s2 = 128; s2 > 0; s2 >>= 1) {
        if (tid < s2) red[tid] += red[tid + s2];
        __syncthreads();
    }
    if (tid == 0) atomicAdd(acc, (double)red[0]);
}

// ---------- global tail + fused finalize (last-block pattern) --------------
__global__ __launch_bounds__(256) void tail_mfma(
    const __hip_bfloat16* __restrict__ Yp, const __hip_bfloat16* __restrict__ Mq,
    const float* __restrict__ bin,
    const short* __restrict__ W2s,
    const float* __restrict__ b2, const float* __restrict__ w3,
    const float* __restrict__ b3,
    int widthIn, double* __restrict__ acc, int* __restrict__ counter,
    float* __restrict__ out)
{
    const int b0 = blockIdx.x * 64;
    const int e = blockIdx.y;
    const int cbase = e * 128;
    const int tid = threadIdx.x;
    const int lane = tid & 63;
    const int wid = tid >> 6;
    const int side = wid >> 1;
    const int wr = wid & 1;

    __shared__ __align__(16) short h1[2 * 64 * 128];
    __shared__ __align__(16) short Bs[128 * 128];
    __shared__ float bins[128], b2s[128], w3s[128];
    __shared__ float red[256];

    const short* W2e = W2s + (long)e * 16384;
    #pragma unroll
    for (int l = 0; l < 8; ++l) {
        int cb = (l * 4 + wid) * 64;
        gll16(W2e + (long)(cb + lane) * 8, &Bs[cb * 8]);
    }
    if (tid < 128) {
        bins[tid] = bin[cbase + tid];
        b2s[tid]  = b2[cbase + tid];
        w3s[tid]  = w3[cbase + tid];
    }
    __syncthreads();

    const short* Ys = (const short*)Yp;
    const short* Ms = (const short*)Mq;
    #pragma unroll
    for (int c = 0; c < 4; ++c) {
        int chunk = c * 256 + tid;
        int row = chunk >> 4, kc = chunk & 15;
        short8 yv = *(const short8*)&Ys[(long)(b0 + row) * widthIn + cbase + kc * 8];
        float yf[8];
        #pragma unroll
        for (int j = 0; j < 8; ++j) yf[j] = bf2f(yv[j]) + bins[kc * 8 + j];
        int dst = row * 128 + (kc ^ (row & 7)) * 8;
        #pragma unroll
        for (int s = 0; s < 2; ++s) {
            int rowm = (b0 + row + s) & (B_ROWS - 1);
            short8 mv = *(const short8*)&Ms[(long)rowm * widthIn + cbase + kc * 8];
            union { short8 v; short sh[8]; } o;
            #pragma unroll
            for (int j = 0; j < 8; ++j)
                o.sh[j] = f2bf_s(fmaxf(yf[j] + bf2f(mv[j]), 0.f));
            *(short8*)&h1[s * 8192 + dst] = o.v;
        }
    }
    __syncthreads();

    const int l15 = lane & 15, l4 = lane >> 4;
    f32x4 accv[2][8] = {};
    #pragma unroll
    for (int st = 0; st < 4; ++st) {
        short8 a[2], b[8];
        #pragma unroll
        for (int m = 0; m < 2; ++m) {
            int row = wr * 32 + m * 16 + l15;
            int ch = (st * 4 + l4) ^ (row & 7);
            a[m] = *(const short8*)&h1[side * 8192 + row * 128 + ch * 8];
        }
        #pragma unroll
        for (int n = 0; n < 8; ++n) {
            int col = n * 16 + l15;
            int ch = (st * 4 + l4) ^ (col & 7);
            b[n] = *(const short8*)&Bs[col * 128 + ch * 8];
        }
        #pragma unroll
        for (int m = 0; m < 2; ++m)
            #pragma unroll
            for (int n = 0; n < 8; ++n)
                accv[m][n] = __builtin_amdgcn_mfma_f32_16x16x32_bf16(a[m], b[n], accv[m][n], 0, 0, 0);
    }

    float p[2][4] = {};
    #pragma unroll
    for (int m = 0; m < 2; ++m)
        #pragma unroll
        for (int n = 0; n < 8; ++n) {
            int colL = n * 16 + l15;
            float bb = b2s[colL], ww = w3s[colL];
            #pragma unroll
            for (int r = 0; r < 4; ++r) {
                float h2 = fmaxf(accv[m][n][r] + bb, 0.f);
                p[m][r] = fmaf(h2, ww, p[m][r]);
            }
        }
    #pragma unroll
    for (int m = 0; m < 2; ++m)
        #pragma unroll
        for (int r = 0; r < 4; ++r)
            #pragma unroll
            for (int off = 1; off < 16; off <<= 1)
                p[m][r] += __shfl_xor(p[m][r], off, 64);

    float mysum = 0.f;
    if (l15 == 0) {
        float bb = b3[e];
        #pragma unroll
        for (int m = 0; m < 2; ++m)
            #pragma unroll
            for (int r = 0; r < 4; ++r) {
                float s = p[m][r] + bb;
                mysum += softplus_f(side ? s : -s);
            }
    }
    red[tid] = mysum;
    __syncthreads();
    for (int s2 = 128; s2 > 0; s2 >>= 1) {
        if (tid < s2) red[tid] += red[tid + s2];
        __syncthreads();
    }
    if (tid == 0) {
        atomicAdd(acc + 1, (double)red[0]);
        __threadfence();
        int old = atomicAdd(counter, 1);
        if (old == (int)(gridDim.x * gridDim.y) - 1) {
            double a0 = atomicAdd(acc + 0, 0.0);
            double a1 = atomicAdd(acc + 1, 0.0);
            out[0] = (float)(a0 / (8192.0 * 16.0) + 0.5 * a1 / 8192.0);
        }
    }
}

extern "C" void kernel_launch(void* const* d_in, const int* in_sizes, int n_in,
                              void* d_out, int out_size, void* d_ws, size_t ws_size,
                              hipStream_t stream)
{
    const float* y   = (const float*)d_in[0];
    const float* M   = (const float*)d_in[1];
    const float* gw0 = (const float*)d_in[2];
    const float* gb0 = (const float*)d_in[3];
    const float* gw1 = (const float*)d_in[4];
    const float* gb1 = (const float*)d_in[5];
    const float* l0w = (const float*)d_in[6];
    const float* l0b = (const float*)d_in[7];
    const float* l1w = (const float*)d_in[8];
    const float* l1b = (const float*)d_in[9];
    const float* l2w = (const float*)d_in[10];
    const float* l2b = (const float*)d_in[11];
    const float* lW1 = (const float*)d_in[12];
    const float* lb1 = (const float*)d_in[13];
    const float* lW2 = (const float*)d_in[14];
    const float* lb2 = (const float*)d_in[15];
    const float* lW3 = (const float*)d_in[16];
    const float* lb3 = (const float*)d_in[17];

    // ---- workspace layout (~127 MB) ----
    char* w = (char*)d_ws;
    double* acc = (double*)w;
    int* counter = (int*)(w + 16);
    float* bing = (float*)(w + 256);
    const size_t MB = 1u << 20;
    __hip_bfloat16* Y1b  = (__hip_bfloat16*)(w + 4096);             // 32 MB
    __hip_bfloat16* Mpb  = (__hip_bfloat16*)(w + 4096 + 32 * MB);   // 32 MB
    __hip_bfloat16* H0b  = (__hip_bfloat16*)(w + 4096 + 64 * MB);   // 16 MB
    short*          Mt2  = (short*)(w + 4096 + 80 * MB);            // 16 MB
    __hip_bfloat16* yb   = (__hip_bfloat16*)(w + 4096 + 96 * MB);   // 16 MB
    __hip_bfloat16* W1yt = (__hip_bfloat16*)(w + 4096 + 112 * MB);  // 4 MB
    __hip_bfloat16* W0p  = (__hip_bfloat16*)(w + 4096 + 118 * MB);  // 2 MB
    __hip_bfloat16* l0wyt = (__hip_bfloat16*)(w + 4096 + 120 * MB); // 256 KB
    short* W2sb = (short*)(w + 4096 + 120 * MB + 512 * 1024);       // 512 KB
    short* L1ws = (short*)(w + 4096 + 121 * MB);                    // 32 KB
    __hip_bfloat16* WgTb = (__hip_bfloat16*)(w + 4096 + 121 * MB + 512 * 1024); // 256 KB
    short* W1m2 = (short*)(w + 4096 + 122 * MB);                    // 512 KB
    __hip_bfloat16* Tyb = (__hip_bfloat16*)(w + 4096 + 123 * MB);   // 2 MB
    __hip_bfloat16* Tgb = (__hip_bfloat16*)(w + 4096 + 125 * MB);   // 2 MB

    dim3 blk(256);

    prep_all<<<dim3(10074), blk, 0, stream>>>(
        y, M, lW1, gw0, l0w, gb1, l0b, lW2, l1w, gw1,
        yb, Mt2, W1yt, W1m2, W0p, l0wyt, bing, W2sb, L1ws, WgTb,
        acc, counter);

    gemm8<<<dim3(1312), dim3(512), 0, stream>>>(
        (const short*)yb, (const short*)W1yt, Y1b,
        Mt2, W1m2, Mpb,
        (const short*)W0p, gb0, H0b,
        (const short*)l0wyt, Tyb);

    tail_plus<<<dim3(2176), blk, 0, stream>>>(
        Y1b, Mpb, lb1, W2sb, lb2, lW3, lb3, acc,
        (const short*)H0b, (const short*)WgTb, Tgb,
        (const short*)yb, (const short*)l0wyt, Tyb);

    tail_mfma<<<dim3(128, 1), blk, 0, stream>>>(
        Tyb, Tgb, bing, L1ws, l1b, l2w, l2b, 128, acc, counter,
        (float*)d_out);
}

// Round 2
// 230.253 us; speedup vs baseline: 1.2526x; 1.2526x over previous
//
#include <hip/hip_runtime.h>
#include <hip/hip_bf16.h>
#include <math.h>

#define B_ROWS 8192
#define NEXP 16

typedef __attribute__((ext_vector_type(8))) short short8;
typedef __attribute__((ext_vector_type(4))) float f32x4;

__device__ __forceinline__ float softplus_f(float x) {
    return fmaxf(x, 0.f) + log1pf(expf(-fabsf(x)));
}

__device__ __forceinline__ float bf2f(short u) {
    union { unsigned int i; float f; } c;
    c.i = ((unsigned int)(unsigned short)u) << 16;
    return c.f;
}

__device__ __forceinline__ short f2bf_s(float x) {
    __hip_bfloat16 h = __float2bfloat16(x);
    return *(short*)&h;
}

__device__ __forceinline__ void gll16(const void* g, void* l) {
    __builtin_amdgcn_global_load_lds(
        (const __attribute__((address_space(1))) void*)g,
        (__attribute__((address_space(3))) void*)l, 16, 0, 0);
}

#define FENCE() asm volatile("" ::: "memory")

// ================= UBER PREP (all prep roles, ONE launch) ==================
// [0,8)          WgT GEMM from RAW f32 (FIRST: long pole overlaps the casts)
// [8,8200)       y cast
// [8200,9224)    Mt2 permute
// [9224,9736)    W1yt tcast
// [9736,9768)    W1m2 zero-padded tcast
// [9768,10024)   W0p prep
// [10024,10056)  l0wyt tcast
// 10056          biasfold + acc/counter zero
// [10057,10074)  W2 swizzle preps
__device__ void cast_body(const float* in, __hip_bfloat16* out, int blk, int tid) {
    int i = blk * 256 + tid;
    float4 v = ((const float4*)in)[i];
    union { ushort4 u; __hip_bfloat16 h[4]; } p;
    p.h[0] = __float2bfloat16(v.x);
    p.h[1] = __float2bfloat16(v.y);
    p.h[2] = __float2bfloat16(v.z);
    p.h[3] = __float2bfloat16(v.w);
    ((ushort4*)out)[i] = p.u;
}

__global__ __launch_bounds__(256) void prep_all(
    const float* __restrict__ y, const float* __restrict__ M,
    const float* __restrict__ lW1, const float* __restrict__ gw0,
    const float* __restrict__ l0w, const float* __restrict__ gb1,
    const float* __restrict__ l0b, const float* __restrict__ lW2,
    const float* __restrict__ l1w, const float* __restrict__ gw1,
    __hip_bfloat16* __restrict__ yb, short* __restrict__ Mt2,
    __hip_bfloat16* __restrict__ W1yt, short* __restrict__ W1m2,
    __hip_bfloat16* __restrict__ W0p, __hip_bfloat16* __restrict__ l0wyt,
    float* __restrict__ bing, short* __restrict__ W2sb,
    short* __restrict__ L1ws, __hip_bfloat16* __restrict__ WgTb,
    double* __restrict__ acc, int* __restrict__ counter)
{
    __shared__ __align__(16) char smem[66048];
    const int b = blockIdx.x;
    const int tid = threadIdx.x;
    const int lane = tid & 63, w = tid >> 6;

    if (b < 8) {
        // ---- WgT[c][j] = sum_o l0w[(1024+o)*128+c]*gw1[j*1024+o], raw f32 ----
        short* As = (short*)smem;
        short* Bs = (short*)(smem + 16384);
        const int bn = b * 128;
        const int wr = w >> 1, wc = w & 1;
        const int l15 = lane & 15, l4 = lane >> 4;

        f32x4 acc4[4][4] = {};
        for (int k0 = 0; k0 < 1024; k0 += 64) {
            {   // stage A: transpose-cast into swizzled image
                int c4 = (tid & 31) * 4;
                int kkr0 = tid >> 5;
                #pragma unroll
                for (int r = 0; r < 8; ++r) {
                    int kk = r * 8 + kkr0;
                    float4 v = *(const float4*)&l0w[(long)(1024 + k0 + kk) * 128 + c4];
                    int g = kk >> 3, sub = kk & 7;
                    #pragma unroll
                    for (int i = 0; i < 4; ++i) {
                        int row = c4 + i;
                        As[row * 64 + (g ^ (row & 7)) * 8 + sub] = f2bf_s(((const float*)&v)[i]);
                    }
                }
            }
            {   // stage B: row-cast into swizzled image
                int jr0 = tid >> 3;
                int g = tid & 7;
                #pragma unroll
                for (int s = 0; s < 4; ++s) {
                    int jrel = s * 32 + jr0;
                    const float* src = &gw1[(long)(bn + jrel) * 1024 + k0 + g * 8];
                    float4 v0 = *(const float4*)src;
                    float4 v1 = *(const float4*)(src + 4);
                    union { short8 v; short sh[8]; } o;
                    o.sh[0] = f2bf_s(v0.x); o.sh[1] = f2bf_s(v0.y);
                    o.sh[2] = f2bf_s(v0.z); o.sh[3] = f2bf_s(v0.w);
                    o.sh[4] = f2bf_s(v1.x); o.sh[5] = f2bf_s(v1.y);
                    o.sh[6] = f2bf_s(v1.z); o.sh[7] = f2bf_s(v1.w);
                    *(short8*)&Bs[jrel * 64 + (g ^ (jrel & 7)) * 8] = o.v;
                }
            }
            __syncthreads();
            #pragma unroll
            for (int st = 0; st < 2; ++st) {
                const int gr = (st * 4 + l4) ^ (l15 & 7);
                short8 a[4], bv[4];
                #pragma unroll
                for (int m = 0; m < 4; ++m)
                    a[m] = *(const short8*)&As[(wr * 64 + m * 16 + l15) * 64 + gr * 8];
                #pragma unroll
                for (int n = 0; n < 4; ++n)
                    bv[n] = *(const short8*)&Bs[(wc * 64 + n * 16 + l15) * 64 + gr * 8];
                #pragma unroll
                for (int m = 0; m < 4; ++m)
                    #pragma unroll
                    for (int n = 0; n < 4; ++n)
                        acc4[m][n] = __builtin_amdgcn_mfma_f32_16x16x32_bf16(a[m], bv[n], acc4[m][n], 0, 0, 0);
            }
            __syncthreads();
        }
        #pragma unroll
        for (int m = 0; m < 4; ++m) {
            int row = wr * 64 + m * 16 + l4 * 4;
            #pragma unroll
            for (int n = 0; n < 4; ++n) {
                int col = bn + wc * 64 + n * 16 + l15;
                #pragma unroll
                for (int r = 0; r < 4; ++r)
                    WgTb[(long)(row + r) * 1024 + col] = __float2bfloat16(acc4[m][n][r]);
            }
        }
        return;
    }

    if (b < 8200) { cast_body(y, yb, b - 8, tid); return; }

    if (b < 9224) {
        // ---- Mt2 permute ----
        short* t = (short*)smem;
        const long r0 = (long)(b - 8200) * 8;
        #pragma unroll
        for (int i = 0; i < 8; ++i) {
            int idx = i * 1024 + tid * 4;
            float4 v = *(const float4*)&M[r0 * 1024 + idx];
            short4 s;
            s.x = f2bf_s(v.x); s.y = f2bf_s(v.y); s.z = f2bf_s(v.z); s.w = f2bf_s(v.w);
            *(short4*)&t[idx] = s;
        }
        __syncthreads();
        const int e = tid & 15, rr = (tid >> 4) & 7, hf = tid >> 7;
        #pragma unroll
        for (int c = 0; c < 4; ++c) {
            union { short8 v; short s[8]; } o;
            #pragma unroll
            for (int j = 0; j < 8; ++j)
                o.s[j] = t[rr * 1024 + (hf * 32 + c * 8 + j) * 16 + e];
            *(short8*)&Mt2[(long)(e >> 1) * (8192L * 128) + (r0 + rr) * 128
                           + (e & 1) * 64 + hf * 32 + c * 8] = o.v;
        }
        return;
    }

    float (*t)[129] = (float(*)[129])smem;

    if (b < 9736) {
        int l = b - 9224, bx = l & 15, by = l >> 4;
        int n0 = bx * 128, k0 = by * 32;
        long base = 64L * 128 + (long)bx * (1088L * 128);
        #pragma unroll
        for (int ll = 0; ll < 16; ++ll) {
            int idx = tid + ll * 256;
            int kk = idx >> 7, nn = idx & 127;
            t[kk][nn] = lW1[base + (long)(k0 + kk) * 128 + nn];
        }
        __syncthreads();
        int nn = tid >> 1, kb = (tid & 1) * 16;
        #pragma unroll
        for (int j = 0; j < 16; ++j)
            W1yt[(long)(n0 + nn) * 1024 + k0 + kb + j] = __float2bfloat16(t[kb + j][nn]);
        return;
    }

    if (b < 9768) {
        int l = b - 9736, bx = l & 15, by = l >> 4;
        int n0 = bx * 128, k0 = by * 32;
        long base = (long)bx * (1088L * 128);
        #pragma unroll
        for (int ll = 0; ll < 16; ++ll) {
            int idx = tid + ll * 256;
            int kk = idx >> 7, nn = idx & 127;
            if (kk < 32) t[kk][nn] = lW1[base + (long)(k0 + kk) * 128 + nn];
        }
        __syncthreads();
        int nn = tid >> 1, kb = (tid & 1) * 16;
        int half = bx & 1;
        #pragma unroll
        for (int j = 0; j < 16; ++j) {
            W1m2[(long)(n0 + nn) * 128 + half * 64 + k0 + kb + j] = f2bf_s(t[kb + j][nn]);
            W1m2[(long)(n0 + nn) * 128 + (1 - half) * 64 + k0 + kb + j] = 0;
        }
        return;
    }

    if (b < 10024) {
        int l = b - 9768, bx = l & 7, by = l >> 3;
        int n0 = bx * 128, k0 = by * 32;
        int e = k0 >> 6, dd0 = k0 & 63;
        #pragma unroll
        for (int ll = 0; ll < 16; ++ll) {
            int idx = tid + ll * 256;
            int kk = idx >> 7, nn = idx & 127;
            t[kk][nn] = gw0[(long)((dd0 + kk) * 16 + e) * 1024 + n0 + nn];
        }
        __syncthreads();
        int nn = tid >> 1, kb = (tid & 1) * 16;
        #pragma unroll
        for (int j = 0; j < 16; ++j)
            W0p[(long)(n0 + nn) * 1024 + k0 + kb + j] = __float2bfloat16(t[kb + j][nn]);
        return;
    }

    if (b < 10056) {
        int by = b - 10024;
        int k0 = by * 32;
        #pragma unroll
        for (int ll = 0; ll < 16; ++ll) {
            int idx = tid + ll * 256;
            int kk = idx >> 7, nn = idx & 127;
            t[kk][nn] = l0w[(long)(k0 + kk) * 128 + nn];
        }
        __syncthreads();
        int nn = tid >> 1, kb = (tid & 1) * 16;
        #pragma unroll
        for (int j = 0; j < 16; ++j)
            l0wyt[(long)nn * 1024 + k0 + kb + j] = __float2bfloat16(t[kb + j][nn]);
        return;
    }

    if (b == 10056) {
        if (tid < 128) {
            float s = l0b[tid];
            for (int o = 0; o < 1024; ++o)
                s = fmaf(gb1[o], l0w[(1024 + o) * 128 + tid], s);
            bing[tid] = s;
        }
        if (tid == 255) { acc[0] = 0.0; acc[1] = 0.0; *counter = 0; }
        return;
    }

    {
        int bb = b - 10057;
        const float* in = (bb < 16) ? lW2 + (long)bb * 16384 : l1w;
        short* out = (bb < 16) ? W2sb + (long)bb * 16384 : L1ws;
        #pragma unroll
        for (int l = 0; l < 64; ++l) {
            int idx = l * 256 + tid;
            t[idx >> 7][idx & 127] = in[idx];
        }
        __syncthreads();
        #pragma unroll
        for (int l = 0; l < 8; ++l) {
            int c = l * 256 + tid;
            int col = c >> 4, kc = c & 15;
            int kcs = kc ^ (col & 7);
            union { short8 v; short s[8]; } u;
            #pragma unroll
            for (int j = 0; j < 8; ++j)
                u.s[j] = f2bf_s(t[kc * 8 + j][col]);
            *(short8*)&out[col * 128 + kcs * 8] = u.v;
        }
    }
}

// ================= MEGA GEMM v6: counted-vmcnt 2-deep pipeline =============
// Geometry/mapping IDENTICAL to the proven 102us v5 (BM=BN=128, 4 waves,
// grid 2624 = 8 XCD x (41 panels x 8 row-chunks), panel-major per XCD ->
// activations L2-resident, FETCH ~68 MB). ONLY the sync structure changes:
// prologue stages tiles 0 and 1; per tile: s_waitcnt vmcnt(8) (tile t
// landed, tile t+1 still in flight) -> raw s_barrier -> ds_read + 32 MFMA
// (setprio) -> s_barrier -> STAGE(t+2) into the buffer just freed.
// vmcnt never drains to 0 inside the loop (T3/T4); drains once at the end.
__global__ __launch_bounds__(256) void gemm_mega6(
    const short* __restrict__ yb, const short* __restrict__ W1yt,
    __hip_bfloat16* __restrict__ Y1b,
    const short* __restrict__ Mt2, const short* __restrict__ W1m2,
    __hip_bfloat16* __restrict__ Mpb,
    const short* __restrict__ W0p, const float* __restrict__ gb0,
    __hip_bfloat16* __restrict__ H0b,
    const short* __restrict__ l0wyt, __hip_bfloat16* __restrict__ Tyb)
{
    __shared__ __align__(16) short As[2][128 * 64];
    __shared__ __align__(16) short Bs[2][128 * 64];
    const int tid = threadIdx.x, lane = tid & 63, w = tid >> 6;
    const int wr = w >> 1, wc = w & 1;
    const int l15 = lane & 15, l4 = lane >> 4;

    const int bid0 = blockIdx.x;
    const int xcd = bid0 & 7;
    const int i = bid0 >> 3;           // [0,328)
    const int bnb = i >> 3;            // panel 0..40 (panel-major within XCD)
    const int rc = i & 7;              // row-chunk within XCD
    const int bm = (xcd * 8 + rc) * 128;

    int grp, bn, K;
    const short* A; const short* Wt; __hip_bfloat16* C; int ldc;
    if (bnb < 16) {
        grp = 0; bn = bnb * 128; A = yb; Wt = W1yt + (long)bn * 1024;
        K = 1024; C = Y1b; ldc = 2048;
    } else if (bnb < 32) {
        int e = bnb - 16; grp = 1; bn = e * 128;
        A = Mt2 + (long)(e >> 1) * (8192L * 128); Wt = W1m2 + (long)bn * 128;
        K = 128; C = Mpb; ldc = 2048;
    } else if (bnb < 40) {
        int c = bnb - 32; grp = 2; bn = c * 128; A = Mt2;
        Wt = W0p + (long)bn * 1024; K = 1024; C = H0b; ldc = 1024;
    } else {
        grp = 3; bn = 0; A = yb; Wt = l0wyt; K = 1024; C = Tyb; ldc = 128;
    }

    const int srow = lane >> 3;
    const int gsrc = (lane & 7) ^ srow;

    auto STAGE = [&](int t) {       // buffer = t & 1; 8 gll16 per wave
        const int buf = t & 1;
        const int k0 = t * 64;
        #pragma unroll
        for (int s = 0; s < 4; ++s) {
            const int rrel = s * 32 + w * 8 + srow;
            const short* asrc;
            if (grp == 2) {
                int g = (k0 >> 3) + gsrc;
                asrc = A + (long)(g >> 4) * (8192L * 128)
                         + (long)(bm + rrel) * 128 + (g & 15) * 8;
            } else {
                asrc = A + (long)(bm + rrel) * K + k0 + gsrc * 8;
            }
            gll16(asrc, &As[buf][(s * 32 + w * 8) * 64]);
            gll16(Wt + (long)rrel * K + k0 + gsrc * 8, &Bs[buf][(s * 32 + w * 8) * 64]);
        }
    };

    f32x4 acc[4][4] = {};
    const int nt = K >> 6;

    auto COMPUTE = [&](int buf) {
        #pragma unroll
        for (int st = 0; st < 2; ++st) {
            const int gr = (st * 4 + l4) ^ (l15 & 7);
            short8 a[4], b[4];
            #pragma unroll
            for (int m = 0; m < 4; ++m)
                a[m] = *(const short8*)&As[buf][(wr * 64 + m * 16 + l15) * 64 + gr * 8];
            #pragma unroll
            for (int n = 0; n < 4; ++n)
                b[n] = *(const short8*)&Bs[buf][(wc * 64 + n * 16 + l15) * 64 + gr * 8];
            __builtin_amdgcn_s_setprio(1);
            #pragma unroll
            for (int m = 0; m < 4; ++m)
                #pragma unroll
                for (int n = 0; n < 4; ++n)
                    acc[m][n] = __builtin_amdgcn_mfma_f32_16x16x32_bf16(a[m], b[n], acc[m][n], 0, 0, 0);
            __builtin_amdgcn_s_setprio(0);
        }
    };

    STAGE(0);
    STAGE(1);
    for (int t = 0; t < nt - 1; ++t) {
        asm volatile("s_waitcnt vmcnt(8)" ::: "memory");  // tile t landed
        __builtin_amdgcn_s_barrier();
        FENCE();
        COMPUTE(t & 1);
        FENCE();
        __builtin_amdgcn_s_barrier();    // all waves done reading buf[t&1]
        FENCE();
        if (t + 2 < nt) STAGE(t + 2);    // overwrite freed buffer
    }
    asm volatile("s_waitcnt vmcnt(0)" ::: "memory");      // last tile landed
    __builtin_amdgcn_s_barrier();
    FENCE();
    COMPUTE((nt - 1) & 1);

    #pragma unroll
    for (int m = 0; m < 4; ++m) {
        int row = bm + wr * 64 + m * 16 + l4 * 4;
        #pragma unroll
        for (int n = 0; n < 4; ++n) {
            int col = bn + wc * 64 + n * 16 + l15;
            float bv = (grp == 2) ? gb0[col] : 0.f;
            #pragma unroll
            for (int r = 0; r < 4; ++r) {
                float v = acc[m][n][r] + bv;
                if (grp == 2) v = fmaxf(v, 0.f);
                C[(long)(row + r) * ldc + col] = __float2bfloat16(v);
            }
        }
    }
}

// ===== tail_plus: [0,2048) local tail (XCD-swz), [2048,2112) Tg GEMM =======
__global__ __launch_bounds__(256) void tail_plus(
    const __hip_bfloat16* __restrict__ Yp, const __hip_bfloat16* __restrict__ Mq,
    const float* __restrict__ bin, const short* __restrict__ W2s,
    const float* __restrict__ b2, const float* __restrict__ w3,
    const float* __restrict__ b3, double* __restrict__ acc,
    const short* __restrict__ H0b, const short* __restrict__ WgTb,
    __hip_bfloat16* __restrict__ Tgb)
{
    __shared__ __align__(16) char smem[68096];
    const int bid = blockIdx.x;
    const int tid = threadIdx.x;
    const int lane = tid & 63;
    const int l15 = lane & 15, l4 = lane >> 4;

    if (bid >= 2048) {
        short* As = (short*)smem;
        short* Bs = (short*)(smem + 16384);
        const int w = tid >> 6;
        const int wr = w >> 1, wc = w & 1;
        const int bm = (bid - 2048) * 128;
        const int srow = lane >> 3;
        const int gsrc = (lane & 7) ^ srow;

        f32x4 a4[4][4] = {};
        for (int k0 = 0; k0 < 1024; k0 += 64) {
            #pragma unroll
            for (int s = 0; s < 4; ++s) {
                const int rrel = s * 32 + w * 8 + srow;
                gll16(H0b + (long)(bm + rrel) * 1024 + k0 + gsrc * 8,
                      As + (s * 32 + w * 8) * 64);
                gll16(WgTb + (long)rrel * 1024 + k0 + gsrc * 8,
                      Bs + (s * 32 + w * 8) * 64);
            }
            __syncthreads();
            #pragma unroll
            for (int st = 0; st < 2; ++st) {
                const int gr = (st * 4 + l4) ^ (l15 & 7);
                short8 a[4], b[4];
                #pragma unroll
                for (int m = 0; m < 4; ++m)
                    a[m] = *(const short8*)&As[(wr * 64 + m * 16 + l15) * 64 + gr * 8];
                #pragma unroll
                for (int n = 0; n < 4; ++n)
                    b[n] = *(const short8*)&Bs[(wc * 64 + n * 16 + l15) * 64 + gr * 8];
                #pragma unroll
                for (int m = 0; m < 4; ++m)
                    #pragma unroll
                    for (int n = 0; n < 4; ++n)
                        a4[m][n] = __builtin_amdgcn_mfma_f32_16x16x32_bf16(a[m], b[n], a4[m][n], 0, 0, 0);
            }
            __syncthreads();
        }
        #pragma unroll
        for (int m = 0; m < 4; ++m) {
            int row = bm + (w >> 1) * 64 + m * 16 + l4 * 4;
            #pragma unroll
            for (int n = 0; n < 4; ++n) {
                int col = (w & 1) * 64 + n * 16 + l15;
                #pragma unroll
                for (int r = 0; r < 4; ++r)
                    Tgb[(long)(row + r) * 128 + col] = __float2bfloat16(a4[m][n][r]);
            }
        }
        return;
    }

    const int wkid = (bid & 7) * 256 + (bid >> 3);
    const int e = wkid & 15;
    const int b0 = (wkid >> 4) * 64;
    const int cbase = e * 128;
    const int wid = tid >> 6;
    const int side = wid >> 1;
    const int wr = wid & 1;
    const int widthIn = 2048;

    short* h1 = (short*)smem;
    short* Bs = (short*)(smem + 32768);
    float* bins = (float*)(smem + 65536);
    float* b2s  = (float*)(smem + 66048);
    float* w3s  = (float*)(smem + 66560);
    float* red  = (float*)(smem + 67072);

    const short* W2e = W2s + (long)e * 16384;
    #pragma unroll
    for (int l = 0; l < 8; ++l) {
        int cb = (l * 4 + wid) * 64;
        gll16(W2e + (long)(cb + lane) * 8, &Bs[cb * 8]);
    }
    if (tid < 128) {
        bins[tid] = bin[cbase + tid];
        b2s[tid]  = b2[cbase + tid];
        w3s[tid]  = w3[cbase + tid];
    }
    __syncthreads();

    const short* Ys = (const short*)Yp;
    const short* Ms = (const short*)Mq;
    #pragma unroll
    for (int c = 0; c < 4; ++c) {
        int chunk = c * 256 + tid;
        int row = chunk >> 4, kc = chunk & 15;
        short8 yv = *(const short8*)&Ys[(long)(b0 + row) * widthIn + cbase + kc * 8];
        float yf[8];
        #pragma unroll
        for (int j = 0; j < 8; ++j) yf[j] = bf2f(yv[j]) + bins[kc * 8 + j];
        int dst = row * 128 + (kc ^ (row & 7)) * 8;
        #pragma unroll
        for (int s = 0; s < 2; ++s) {
            int rowm = (b0 + row + s) & (B_ROWS - 1);
            short8 mv = *(const short8*)&Ms[(long)rowm * widthIn + cbase + kc * 8];
            union { short8 v; short sh[8]; } o;
            #pragma unroll
            for (int j = 0; j < 8; ++j)
                o.sh[j] = f2bf_s(fmaxf(yf[j] + bf2f(mv[j]), 0.f));
            *(short8*)&h1[s * 8192 + dst] = o.v;
        }
    }
    __syncthreads();

    f32x4 accv[2][8] = {};
    #pragma unroll
    for (int st = 0; st < 4; ++st) {
        short8 a[2], b[8];
        #pragma unroll
        for (int m = 0; m < 2; ++m) {
            int row = wr * 32 + m * 16 + l15;
            int ch = (st * 4 + l4) ^ (row & 7);
            a[m] = *(const short8*)&h1[side * 8192 + row * 128 + ch * 8];
        }
        #pragma unroll
        for (int n = 0; n < 8; ++n) {
            int col = n * 16 + l15;
            int ch = (st * 4 + l4) ^ (col & 7);
            b[n] = *(const short8*)&Bs[col * 128 + ch * 8];
        }
        #pragma unroll
        for (int m = 0; m < 2; ++m)
            #pragma unroll
            for (int n = 0; n < 8; ++n)
                accv[m][n] = __builtin_amdgcn_mfma_f32_16x16x32_bf16(a[m], b[n], accv[m][n], 0, 0, 0);
    }

    float p[2][4] = {};
    #pragma unroll
    for (int m = 0; m < 2; ++m)
        #pragma unroll
        for (int n = 0; n < 8; ++n) {
            int colL = n * 16 + l15;
            float bb = b2s[colL], ww = w3s[colL];
            #pragma unroll
            for (int r = 0; r < 4; ++r) {
                float h2 = fmaxf(accv[m][n][r] + bb, 0.f);
                p[m][r] = fmaf(h2, ww, p[m][r]);
            }
        }
    #pragma unroll
    for (int m = 0; m < 2; ++m)
        #pragma unroll
        for (int r = 0; r < 4; ++r)
            #pragma unroll
            for (int off = 1; off < 16; off <<= 1)
                p[m][r] += __shfl_xor(p[m][r], off, 64);

    float mysum = 0.f;
    if (l15 == 0) {
        float bb = b3[e];
        #pragma unroll
        for (int m = 0; m < 2; ++m)
            #pragma unroll
            for (int r = 0; r < 4; ++r) {
                float s = p[m][r] + bb;
                mysum += softplus_f(side ? s : -s);
            }
    }
    red[tid] = mysum;
    __syncthreads();
    for (int s2 = 128; s2 > 0; s2 >>= 1) {
        if (tid < s2) red[tid] += red[tid + s2];
        __syncthreads();
    }
    if (tid == 0) atomicAdd(acc, (double)red[0]);
}

// ---------- global tail + fused finalize (last-block pattern) --------------
__global__ __launch_bounds__(256) void tail_mfma(
    const __hip_bfloat16* __restrict__ Yp, const __hip_bfloat16* __restrict__ Mq,
    const float* __restrict__ bin,
    const short* __restrict__ W2s,
    const float* __restrict__ b2, const float* __restrict__ w3,
    const float* __restrict__ b3,
    int widthIn, double* __restrict__ acc, int* __restrict__ counter,
    float* __restrict__ out)
{
    const int b0 = blockIdx.x * 64;
    const int e = blockIdx.y;
    const int cbase = e * 128;
    const int tid = threadIdx.x;
    const int lane = tid & 63;
    const int wid = tid >> 6;
    const int side = wid >> 1;
    const int wr = wid & 1;

    __shared__ __align__(16) short h1[2 * 64 * 128];
    __shared__ __align__(16) short Bs[128 * 128];
    __shared__ float bins[128], b2s[128], w3s[128];
    __shared__ float red[256];

    const short* W2e = W2s + (long)e * 16384;
    #pragma unroll
    for (int l = 0; l < 8; ++l) {
        int cb = (l * 4 + wid) * 64;
        gll16(W2e + (long)(cb + lane) * 8, &Bs[cb * 8]);
    }
    if (tid < 128) {
        bins[tid] = bin[cbase + tid];
        b2s[tid]  = b2[cbase + tid];
        w3s[tid]  = w3[cbase + tid];
    }
    __syncthreads();

    const short* Ys = (const short*)Yp;
    const short* Ms = (const short*)Mq;
    #pragma unroll
    for (int c = 0; c < 4; ++c) {
        int chunk = c * 256 + tid;
        int row = chunk >> 4, kc = chunk & 15;
        short8 yv = *(const short8*)&Ys[(long)(b0 + row) * widthIn + cbase + kc * 8];
        float yf[8];
        #pragma unroll
        for (int j = 0; j < 8; ++j) yf[j] = bf2f(yv[j]) + bins[kc * 8 + j];
        int dst = row * 128 + (kc ^ (row & 7)) * 8;
        #pragma unroll
        for (int s = 0; s < 2; ++s) {
            int rowm = (b0 + row + s) & (B_ROWS - 1);
            short8 mv = *(const short8*)&Ms[(long)rowm * widthIn + cbase + kc * 8];
            union { short8 v; short sh[8]; } o;
            #pragma unroll
            for (int j = 0; j < 8; ++j)
                o.sh[j] = f2bf_s(fmaxf(yf[j] + bf2f(mv[j]), 0.f));
            *(short8*)&h1[s * 8192 + dst] = o.v;
        }
    }
    __syncthreads();

    const int l15 = lane & 15, l4 = lane >> 4;
    f32x4 accv[2][8] = {};
    #pragma unroll
    for (int st = 0; st < 4; ++st) {
        short8 a[2], b[8];
        #pragma unroll
        for (int m = 0; m < 2; ++m) {
            int row = wr * 32 + m * 16 + l15;
            int ch = (st * 4 + l4) ^ (row & 7);
            a[m] = *(const short8*)&h1[side * 8192 + row * 128 + ch * 8];
        }
        #pragma unroll
        for (int n = 0; n < 8; ++n) {
            int col = n * 16 + l15;
            int ch = (st * 4 + l4) ^ (col & 7);
            b[n] = *(const short8*)&Bs[col * 128 + ch * 8];
        }
        #pragma unroll
        for (int m = 0; m < 2; ++m)
            #pragma unroll
            for (int n = 0; n < 8; ++n)
                accv[m][n] = __builtin_amdgcn_mfma_f32_16x16x32_bf16(a[m], b[n], accv[m][n], 0, 0, 0);
    }

    float p[2][4] = {};
    #pragma unroll
    for (int m = 0; m < 2; ++m)
        #pragma unroll
        for (int n = 0; n < 8; ++n) {
            int colL = n * 16 + l15;
            float bb = b2s[colL], ww = w3s[colL];
            #pragma unroll
            for (int r = 0; r < 4; ++r) {
                float h2 = fmaxf(accv[m][n][r] + bb, 0.f);
                p[m][r] = fmaf(h2, ww, p[m][r]);
            }
        }
    #pragma unroll
    for (int m = 0; m < 2; ++m)
        #pragma unroll
        for (int r = 0; r < 4; ++r)
            #pragma unroll
            for (int off = 1; off < 16; off <<= 1)
                p[m][r] += __shfl_xor(p[m][r], off, 64);

    float mysum = 0.f;
    if (l15 == 0) {
        float bb = b3[e];
        #pragma unroll
        for (int m = 0; m < 2; ++m)
            #pragma unroll
            for (int r = 0; r < 4; ++r) {
                float s = p[m][r] + bb;
                mysum += softplus_f(side ? s : -s);
            }
    }
    red[tid] = mysum;
    __syncthreads();
    for (int s2 = 128; s2 > 0; s2 >>= 1) {
        if (tid < s2) red[tid] += red[tid + s2];
        __syncthreads();
    }
    if (tid == 0) {
        atomicAdd(acc + 1, (double)red[0]);
        __threadfence();
        int old = atomicAdd(counter, 1);
        if (old == (int)(gridDim.x * gridDim.y) - 1) {
            double a0 = atomicAdd(acc + 0, 0.0);
            double a1 = atomicAdd(acc + 1, 0.0);
            out[0] = (float)(a0 / (8192.0 * 16.0) + 0.5 * a1 / 8192.0);
        }
    }
}

extern "C" void kernel_launch(void* const* d_in, const int* in_sizes, int n_in,
                              void* d_out, int out_size, void* d_ws, size_t ws_size,
                              hipStream_t stream)
{
    const float* y   = (const float*)d_in[0];
    const float* M   = (const float*)d_in[1];
    const float* gw0 = (const float*)d_in[2];
    const float* gb0 = (const float*)d_in[3];
    const float* gw1 = (const float*)d_in[4];
    const float* gb1 = (const float*)d_in[5];
    const float* l0w = (const float*)d_in[6];
    const float* l0b = (const float*)d_in[7];
    const float* l1w = (const float*)d_in[8];
    const float* l1b = (const float*)d_in[9];
    const float* l2w = (const float*)d_in[10];
    const float* l2b = (const float*)d_in[11];
    const float* lW1 = (const float*)d_in[12];
    const float* lb1 = (const float*)d_in[13];
    const float* lW2 = (const float*)d_in[14];
    const float* lb2 = (const float*)d_in[15];
    const float* lW3 = (const float*)d_in[16];
    const float* lb3 = (const float*)d_in[17];

    // ---- workspace layout (~127 MB) ----
    char* w = (char*)d_ws;
    double* acc = (double*)w;
    int* counter = (int*)(w + 16);
    float* bing = (float*)(w + 256);
    const size_t MB = 1u << 20;
    __hip_bfloat16* Y1b  = (__hip_bfloat16*)(w + 4096);             // 32 MB
    __hip_bfloat16* Mpb  = (__hip_bfloat16*)(w + 4096 + 32 * MB);   // 32 MB
    __hip_bfloat16* H0b  = (__hip_bfloat16*)(w + 4096 + 64 * MB);   // 16 MB
    short*          Mt2  = (short*)(w + 4096 + 80 * MB);            // 16 MB
    __hip_bfloat16* yb   = (__hip_bfloat16*)(w + 4096 + 96 * MB);   // 16 MB
    __hip_bfloat16* W1yt = (__hip_bfloat16*)(w + 4096 + 112 * MB);  // 4 MB
    __hip_bfloat16* W0p  = (__hip_bfloat16*)(w + 4096 + 118 * MB);  // 2 MB
    __hip_bfloat16* l0wyt = (__hip_bfloat16*)(w + 4096 + 120 * MB); // 256 KB
    short* W2sb = (short*)(w + 4096 + 120 * MB + 512 * 1024);       // 512 KB
    short* L1ws = (short*)(w + 4096 + 121 * MB);                    // 32 KB
    __hip_bfloat16* WgTb = (__hip_bfloat16*)(w + 4096 + 121 * MB + 512 * 1024); // 256 KB
    short* W1m2 = (short*)(w + 4096 + 122 * MB);                    // 512 KB
    __hip_bfloat16* Tyb = (__hip_bfloat16*)(w + 4096 + 123 * MB);   // 2 MB
    __hip_bfloat16* Tgb = (__hip_bfloat16*)(w + 4096 + 125 * MB);   // 2 MB

    dim3 blk(256);

    prep_all<<<dim3(10074), blk, 0, stream>>>(
        y, M, lW1, gw0, l0w, gb1, l0b, lW2, l1w, gw1,
        yb, Mt2, W1yt, W1m2, W0p, l0wyt, bing, W2sb, L1ws, WgTb,
        acc, counter);

    gemm_mega6<<<dim3(2624), blk, 0, stream>>>(
        (const short*)yb, (const short*)W1yt, Y1b,
        Mt2, W1m2, Mpb,
        (const short*)W0p, gb0, H0b,
        (const short*)l0wyt, Tyb);

    tail_plus<<<dim3(2112), blk, 0, stream>>>(
        Y1b, Mpb, lb1, W2sb, lb2, lW3, lb3, acc,
        (const short*)H0b, (const short*)WgTb, Tgb);

    tail_mfma<<<dim3(128, 1), blk, 0, stream>>>(
        Tyb, Tgb, bing, L1ws, l1b, l2w, l2b, 128, acc, counter,
        (float*)d_out);
}

// Round 3
// 212.775 us; speedup vs baseline: 1.3555x; 1.0821x over previous
//
#include <hip/hip_runtime.h>
#include <hip/hip_bf16.h>
#include <math.h>

#define B_ROWS 8192
#define NEXP 16

typedef __attribute__((ext_vector_type(8))) short short8;
typedef __attribute__((ext_vector_type(4))) float f32x4;

__device__ __forceinline__ float softplus_f(float x) {
    return fmaxf(x, 0.f) + log1pf(expf(-fabsf(x)));
}

__device__ __forceinline__ float bf2f(short u) {
    union { unsigned int i; float f; } c;
    c.i = ((unsigned int)(unsigned short)u) << 16;
    return c.f;
}

__device__ __forceinline__ short f2bf_s(float x) {
    __hip_bfloat16 h = __float2bfloat16(x);
    return *(short*)&h;
}

__device__ __forceinline__ void gll16(const void* g, void* l) {
    __builtin_amdgcn_global_load_lds(
        (const __attribute__((address_space(1))) void*)g,
        (__attribute__((address_space(3))) void*)l, 16, 0, 0);
}

#define FENCE() asm volatile("" ::: "memory")
#define VM8 asm volatile("s_waitcnt vmcnt(8)" ::: "memory")
#define VM4 asm volatile("s_waitcnt vmcnt(4)" ::: "memory")
#define VM0 asm volatile("s_waitcnt vmcnt(0)" ::: "memory")
#define BAR __builtin_amdgcn_s_barrier()

// ================= UBER PREP (all prep roles, ONE launch) ==================
__device__ void cast_body(const float* in, __hip_bfloat16* out, int blk, int tid) {
    int i = blk * 256 + tid;
    float4 v = ((const float4*)in)[i];
    union { ushort4 u; __hip_bfloat16 h[4]; } p;
    p.h[0] = __float2bfloat16(v.x);
    p.h[1] = __float2bfloat16(v.y);
    p.h[2] = __float2bfloat16(v.z);
    p.h[3] = __float2bfloat16(v.w);
    ((ushort4*)out)[i] = p.u;
}

__global__ __launch_bounds__(256) void prep_all(
    const float* __restrict__ y, const float* __restrict__ M,
    const float* __restrict__ lW1, const float* __restrict__ gw0,
    const float* __restrict__ l0w, const float* __restrict__ gb1,
    const float* __restrict__ l0b, const float* __restrict__ lW2,
    const float* __restrict__ l1w, const float* __restrict__ gw1,
    __hip_bfloat16* __restrict__ yb, short* __restrict__ Mt2,
    __hip_bfloat16* __restrict__ W1yt, short* __restrict__ W1m2,
    __hip_bfloat16* __restrict__ W0p, __hip_bfloat16* __restrict__ l0wyt,
    float* __restrict__ bing, short* __restrict__ W2sb,
    short* __restrict__ L1ws, __hip_bfloat16* __restrict__ WgTb,
    double* __restrict__ acc, int* __restrict__ counter)
{
    __shared__ __align__(16) char smem[66048];
    const int b = blockIdx.x;
    const int tid = threadIdx.x;
    const int lane = tid & 63, w = tid >> 6;

    if (b < 8) {
        short* As = (short*)smem;
        short* Bs = (short*)(smem + 16384);
        const int bn = b * 128;
        const int wr = w >> 1, wc = w & 1;
        const int l15 = lane & 15, l4 = lane >> 4;

        f32x4 acc4[4][4] = {};
        for (int k0 = 0; k0 < 1024; k0 += 64) {
            {
                int c4 = (tid & 31) * 4;
                int kkr0 = tid >> 5;
                #pragma unroll
                for (int r = 0; r < 8; ++r) {
                    int kk = r * 8 + kkr0;
                    float4 v = *(const float4*)&l0w[(long)(1024 + k0 + kk) * 128 + c4];
                    int g = kk >> 3, sub = kk & 7;
                    #pragma unroll
                    for (int i = 0; i < 4; ++i) {
                        int row = c4 + i;
                        As[row * 64 + (g ^ (row & 7)) * 8 + sub] = f2bf_s(((const float*)&v)[i]);
                    }
                }
            }
            {
                int jr0 = tid >> 3;
                int g = tid & 7;
                #pragma unroll
                for (int s = 0; s < 4; ++s) {
                    int jrel = s * 32 + jr0;
                    const float* src = &gw1[(long)(bn + jrel) * 1024 + k0 + g * 8];
                    float4 v0 = *(const float4*)src;
                    float4 v1 = *(const float4*)(src + 4);
                    union { short8 v; short sh[8]; } o;
                    o.sh[0] = f2bf_s(v0.x); o.sh[1] = f2bf_s(v0.y);
                    o.sh[2] = f2bf_s(v0.z); o.sh[3] = f2bf_s(v0.w);
                    o.sh[4] = f2bf_s(v1.x); o.sh[5] = f2bf_s(v1.y);
                    o.sh[6] = f2bf_s(v1.z); o.sh[7] = f2bf_s(v1.w);
                    *(short8*)&Bs[jrel * 64 + (g ^ (jrel & 7)) * 8] = o.v;
                }
            }
            __syncthreads();
            #pragma unroll
            for (int st = 0; st < 2; ++st) {
                const int gr = (st * 4 + l4) ^ (l15 & 7);
                short8 a[4], bv[4];
                #pragma unroll
                for (int m = 0; m < 4; ++m)
                    a[m] = *(const short8*)&As[(wr * 64 + m * 16 + l15) * 64 + gr * 8];
                #pragma unroll
                for (int n = 0; n < 4; ++n)
                    bv[n] = *(const short8*)&Bs[(wc * 64 + n * 16 + l15) * 64 + gr * 8];
                #pragma unroll
                for (int m = 0; m < 4; ++m)
                    #pragma unroll
                    for (int n = 0; n < 4; ++n)
                        acc4[m][n] = __builtin_amdgcn_mfma_f32_16x16x32_bf16(a[m], bv[n], acc4[m][n], 0, 0, 0);
            }
            __syncthreads();
        }
        #pragma unroll
        for (int m = 0; m < 4; ++m) {
            int row = wr * 64 + m * 16 + l4 * 4;
            #pragma unroll
            for (int n = 0; n < 4; ++n) {
                int col = bn + wc * 64 + n * 16 + l15;
                #pragma unroll
                for (int r = 0; r < 4; ++r)
                    WgTb[(long)(row + r) * 1024 + col] = __float2bfloat16(acc4[m][n][r]);
            }
        }
        return;
    }

    if (b < 8200) { cast_body(y, yb, b - 8, tid); return; }

    if (b < 9224) {
        short* t = (short*)smem;
        const long r0 = (long)(b - 8200) * 8;
        #pragma unroll
        for (int i = 0; i < 8; ++i) {
            int idx = i * 1024 + tid * 4;
            float4 v = *(const float4*)&M[r0 * 1024 + idx];
            short4 s;
            s.x = f2bf_s(v.x); s.y = f2bf_s(v.y); s.z = f2bf_s(v.z); s.w = f2bf_s(v.w);
            *(short4*)&t[idx] = s;
        }
        __syncthreads();
        const int e = tid & 15, rr = (tid >> 4) & 7, hf = tid >> 7;
        #pragma unroll
        for (int c = 0; c < 4; ++c) {
            union { short8 v; short s[8]; } o;
            #pragma unroll
            for (int j = 0; j < 8; ++j)
                o.s[j] = t[rr * 1024 + (hf * 32 + c * 8 + j) * 16 + e];
            *(short8*)&Mt2[(long)(e >> 1) * (8192L * 128) + (r0 + rr) * 128
                           + (e & 1) * 64 + hf * 32 + c * 8] = o.v;
        }
        return;
    }

    float (*t)[129] = (float(*)[129])smem;

    if (b < 9736) {
        int l = b - 9224, bx = l & 15, by = l >> 4;
        int n0 = bx * 128, k0 = by * 32;
        long base = 64L * 128 + (long)bx * (1088L * 128);
        #pragma unroll
        for (int ll = 0; ll < 16; ++ll) {
            int idx = tid + ll * 256;
            int kk = idx >> 7, nn = idx & 127;
            t[kk][nn] = lW1[base + (long)(k0 + kk) * 128 + nn];
        }
        __syncthreads();
        int nn = tid >> 1, kb = (tid & 1) * 16;
        #pragma unroll
        for (int j = 0; j < 16; ++j)
            W1yt[(long)(n0 + nn) * 1024 + k0 + kb + j] = __float2bfloat16(t[kb + j][nn]);
        return;
    }

    if (b < 9768) {
        int l = b - 9736, bx = l & 15, by = l >> 4;
        int n0 = bx * 128, k0 = by * 32;
        long base = (long)bx * (1088L * 128);
        #pragma unroll
        for (int ll = 0; ll < 16; ++ll) {
            int idx = tid + ll * 256;
            int kk = idx >> 7, nn = idx & 127;
            if (kk < 32) t[kk][nn] = lW1[base + (long)(k0 + kk) * 128 + nn];
        }
        __syncthreads();
        int nn = tid >> 1, kb = (tid & 1) * 16;
        int half = bx & 1;
        #pragma unroll
        for (int j = 0; j < 16; ++j) {
            W1m2[(long)(n0 + nn) * 128 + half * 64 + k0 + kb + j] = f2bf_s(t[kb + j][nn]);
            W1m2[(long)(n0 + nn) * 128 + (1 - half) * 64 + k0 + kb + j] = 0;
        }
        return;
    }

    if (b < 10024) {
        int l = b - 9768, bx = l & 7, by = l >> 3;
        int n0 = bx * 128, k0 = by * 32;
        int e = k0 >> 6, dd0 = k0 & 63;
        #pragma unroll
        for (int ll = 0; ll < 16; ++ll) {
            int idx = tid + ll * 256;
            int kk = idx >> 7, nn = idx & 127;
            t[kk][nn] = gw0[(long)((dd0 + kk) * 16 + e) * 1024 + n0 + nn];
        }
        __syncthreads();
        int nn = tid >> 1, kb = (tid & 1) * 16;
        #pragma unroll
        for (int j = 0; j < 16; ++j)
            W0p[(long)(n0 + nn) * 1024 + k0 + kb + j] = __float2bfloat16(t[kb + j][nn]);
        return;
    }

    if (b < 10056) {
        int by = b - 10024;
        int k0 = by * 32;
        #pragma unroll
        for (int ll = 0; ll < 16; ++ll) {
            int idx = tid + ll * 256;
            int kk = idx >> 7, nn = idx & 127;
            t[kk][nn] = l0w[(long)(k0 + kk) * 128 + nn];
        }
        __syncthreads();
        int nn = tid >> 1, kb = (tid & 1) * 16;
        #pragma unroll
        for (int j = 0; j < 16; ++j)
            l0wyt[(long)nn * 1024 + k0 + kb + j] = __float2bfloat16(t[kb + j][nn]);
        return;
    }

    if (b == 10056) {
        if (tid < 128) {
            float s = l0b[tid];
            for (int o = 0; o < 1024; ++o)
                s = fmaf(gb1[o], l0w[(1024 + o) * 128 + tid], s);
            bing[tid] = s;
        }
        if (tid == 255) { acc[0] = 0.0; acc[1] = 0.0; *counter = 0; }
        return;
    }

    {
        int bb = b - 10057;
        const float* in = (bb < 16) ? lW2 + (long)bb * 16384 : l1w;
        short* out = (bb < 16) ? W2sb + (long)bb * 16384 : L1ws;
        #pragma unroll
        for (int l = 0; l < 64; ++l) {
            int idx = l * 256 + tid;
            t[idx >> 7][idx & 127] = in[idx];
        }
        __syncthreads();
        #pragma unroll
        for (int l = 0; l < 8; ++l) {
            int c = l * 256 + tid;
            int col = c >> 4, kc = c & 15;
            int kcs = kc ^ (col & 7);
            union { short8 v; short s[8]; } u;
            #pragma unroll
            for (int j = 0; j < 8; ++j)
                u.s[j] = f2bf_s(t[kc * 8 + j][col]);
            *(short8*)&out[col * 128 + kcs * 8] = u.v;
        }
    }
}

// ============ GEMM 8-PHASE: 256^2 tile, counted-vmcnt pipeline =============
// BM=BN=256, BK=64, 512 thr / 8 waves (2M x 4N), per-wave 128x64, acc[8][4].
// LDS 128 KB: {A,B} x {slot 0,1} x {khalf 0,1} 16 KB regions, layout
// [256 rows][4 slots of 16B] with slot = g ^ (row&3)  (2-way max = free).
// Phase (slot s, khalf k, mhalf h): 8 ds_read_b128 + 1 half-tile stage
// (2 gll16/wave) + [vmcnt(8) at even phases] + barrier + setprio 16 MFMA +
// barrier. Region ledger (2 loads/wave/phase, verified by hand):
//   ph1:A(1,k1)<-T0+1 ph2:B(1,k1) ph3:A(0,k0)<-T0+2 ph4:B(0,k0)
//   ph5:A(0,k1)<-T0+2 ph6:B(0,k1) ph7:A(1,k0)<-T0+3 ph8:B(1,k0)
// Each even-phase vmcnt(8) lands exactly the region read one phase later
// (lead 5-6 phases ~ 1000cyc > 900cyc HBM). Peeled last iter: 8 -> 4 -> 0.
// Mapping: bid = idx*8 + xcd; per XCD its 4 row-tiles (1024 rows, L2-res):
// idx[0,32)=grp0 (yb@W1yt->Y1b), [32,48)=grp2 (Mt2@W0p->H0b),
// [48,80)=grp1 (Mt2@W1m2->Mpb, K=128). grp3 lives in tail_plus.
__global__ __launch_bounds__(512, 2) void gemm8ph(
    const short* __restrict__ yb, const short* __restrict__ W1yt,
    __hip_bfloat16* __restrict__ Y1b,
    const short* __restrict__ Mt2, const short* __restrict__ W1m2,
    __hip_bfloat16* __restrict__ Mpb,
    const short* __restrict__ W0p, const float* __restrict__ gb0,
    __hip_bfloat16* __restrict__ H0b)
{
    __shared__ __align__(16) char smem[131072];
    const int tid = threadIdx.x;
    const int lane = tid & 63, w = tid >> 6;
    const int l15 = lane & 15, l4 = lane >> 4;
    const int wr = w >> 2, wc = w & 3;

    const int bid = blockIdx.x;
    const int xcd = bid & 7;
    const int idx = bid >> 3;

    int grp, bm, bn, K;
    const short* A; const short* Wt; __hip_bfloat16* C; int ldc;
    if (idx < 32) {
        grp = 0; bm = (xcd * 4 + (idx >> 3)) * 256; bn = (idx & 7) * 256;
        A = yb; Wt = W1yt + (long)bn * 1024; K = 1024; C = Y1b; ldc = 2048;
    } else if (idx < 48) {
        int j = idx - 32;
        grp = 2; bm = (xcd * 4 + (j >> 2)) * 256; bn = (j & 3) * 256;
        A = Mt2; Wt = W0p + (long)bn * 1024; K = 1024; C = H0b; ldc = 1024;
    } else {
        int j = idx - 48;
        grp = 1; bm = (xcd * 4 + (j >> 3)) * 256; bn = (j & 7) * 256;
        A = Mt2 + (long)(bn >> 8) * (8192L * 128);
        Wt = W1m2 + (long)bn * 128; K = 128; C = Mpb; ldc = 2048;
    }
    const int nt = K >> 6;

    // staging: lane i -> row sub = i>>2, slot = i&3; source kgroup pre-XOR'd
    const int sR = lane >> 2;
    const int sG = (lane & 3) ^ (sR & 3);

    auto STAGE_A = [&](int s, int k, int t) {
        #pragma unroll
        for (int blk = 0; blk < 2; ++blk) {
            const int row = w * 32 + blk * 16 + sR;
            const short* src;
            if (grp == 2) {
                const int g = t * 8 + k * 4 + sG;
                src = A + (long)(g >> 4) * (8192L * 128)
                        + (long)(bm + row) * 128 + (g & 15) * 8;
            } else {
                src = A + (long)(bm + row) * K + t * 64 + k * 32 + sG * 8;
            }
            gll16(src, smem + s * 32768 + k * 16384 + w * 2048 + blk * 1024);
        }
    };
    auto STAGE_B = [&](int s, int k, int t) {
        #pragma unroll
        for (int blk = 0; blk < 2; ++blk) {
            const int row = w * 32 + blk * 16 + sR;
            gll16(Wt + (long)row * K + t * 64 + k * 32 + sG * 8,
                  smem + 65536 + s * 32768 + k * 16384 + w * 2048 + blk * 1024);
        }
    };

    f32x4 acc[8][4] = {};
    const int xr = (l4 ^ (l15 & 3)) * 16;
    const int aOff = (wr * 128 + l15) * 64 + xr;
    const int bOff = (wc * 64 + l15) * 64 + xr;

#define PHASE(s, k, h, STG, WT) do {                                          \
    short8 a_[4], b_[4];                                                      \
    const int RO = (s) * 32768 + (k) * 16384;                                 \
    _Pragma("unroll")                                                         \
    for (int mm = 0; mm < 4; ++mm)                                            \
        a_[mm] = *(const short8*)(smem + RO + aOff + (h) * 4096 + mm * 1024); \
    _Pragma("unroll")                                                         \
    for (int n = 0; n < 4; ++n)                                               \
        b_[n] = *(const short8*)(smem + 65536 + RO + bOff + n * 1024);        \
    STG; WT; FENCE(); BAR; FENCE();                                           \
    __builtin_amdgcn_s_setprio(1);                                            \
    _Pragma("unroll")                                                         \
    for (int mm = 0; mm < 4; ++mm)                                            \
        _Pragma("unroll")                                                     \
        for (int n = 0; n < 4; ++n)                                           \
            acc[(h) * 4 + mm][n] = __builtin_amdgcn_mfma_f32_16x16x32_bf16(   \
                a_[mm], b_[n], acc[(h) * 4 + mm][n], 0, 0, 0);                \
    __builtin_amdgcn_s_setprio(0);                                            \
    FENCE(); BAR; FENCE();                                                    \
} while (0)

    // prologue: tile0 (k0,k1) + tile1 (k0) = 12 loads; vmcnt(8) -> (0,k0) in
    STAGE_A(0, 0, 0); STAGE_B(0, 0, 0);
    STAGE_A(0, 1, 0); STAGE_B(0, 1, 0);
    STAGE_A(1, 0, 1); STAGE_B(1, 0, 1);
    VM8; FENCE(); BAR; FENCE();

    const int ni = nt >> 1;
    for (int i = 0; i < ni - 1; ++i) {
        const int T0 = i * 2;
        PHASE(0, 0, 0, STAGE_A(1, 1, T0 + 1), {});
        PHASE(0, 0, 1, STAGE_B(1, 1, T0 + 1), VM8);
        PHASE(0, 1, 0, STAGE_A(0, 0, T0 + 2), {});
        PHASE(0, 1, 1, STAGE_B(0, 0, T0 + 2), VM8);
        PHASE(1, 0, 0, STAGE_A(0, 1, T0 + 2), {});
        PHASE(1, 0, 1, STAGE_B(0, 1, T0 + 2), VM8);
        PHASE(1, 1, 0, STAGE_A(1, 0, T0 + 3), {});
        PHASE(1, 1, 1, STAGE_B(1, 0, T0 + 3), VM8);
    }
    {   // peeled last iteration (tiles nt-2, nt-1): drain 8 -> 4 -> 0
        const int T0 = nt - 2;
        PHASE(0, 0, 0, STAGE_A(1, 1, T0 + 1), {});
        PHASE(0, 0, 1, STAGE_B(1, 1, T0 + 1), VM8);
        PHASE(0, 1, 0, {}, {});
        PHASE(0, 1, 1, {}, VM4);
        PHASE(1, 0, 0, {}, {});
        PHASE(1, 0, 1, {}, VM0);
        PHASE(1, 1, 0, {}, {});
        PHASE(1, 1, 1, {}, {});
    }
#undef PHASE

    #pragma unroll
    for (int m = 0; m < 8; ++m) {
        const int row = bm + wr * 128 + m * 16 + l4 * 4;
        #pragma unroll
        for (int n = 0; n < 4; ++n) {
            const int col = bn + wc * 64 + n * 16 + l15;
            const float bv = (grp == 2) ? gb0[col] : 0.f;
            #pragma unroll
            for (int r = 0; r < 4; ++r) {
                float v = acc[m][n][r] + bv;
                if (grp == 2) v = fmaxf(v, 0.f);
                C[(long)(row + r) * ldc + col] = __float2bfloat16(v);
            }
        }
    }
}

// ===== tail_plus: [0,2048) local tail (XCD-swz), [2048,2112) Tg GEMM,
//                  [2112,2176) Ty GEMM (grp3, moved out of the mega GEMM) ===
__global__ __launch_bounds__(256) void tail_plus(
    const __hip_bfloat16* __restrict__ Yp, const __hip_bfloat16* __restrict__ Mq,
    const float* __restrict__ bin, const short* __restrict__ W2s,
    const float* __restrict__ b2, const float* __restrict__ w3,
    const float* __restrict__ b3, double* __restrict__ acc,
    const short* __restrict__ H0b, const short* __restrict__ WgTb,
    __hip_bfloat16* __restrict__ Tgb,
    const short* __restrict__ ybs, const short* __restrict__ l0ws,
    __hip_bfloat16* __restrict__ Tyb)
{
    __shared__ __align__(16) char smem[68096];
    const int bid = blockIdx.x;
    const int tid = threadIdx.x;
    const int lane = tid & 63;
    const int l15 = lane & 15, l4 = lane >> 4;

    if (bid >= 2048) {
        const int sel = bid - 2048;
        const short* Ain = (sel < 64) ? H0b : ybs;
        const short* Bin = (sel < 64) ? WgTb : l0ws;
        __hip_bfloat16* Co = (sel < 64) ? Tgb : Tyb;
        short* As = (short*)smem;
        short* Bs = (short*)(smem + 16384);
        const int w = tid >> 6;
        const int wr = w >> 1, wc = w & 1;
        const int bm = (sel & 63) * 128;
        const int srow = lane >> 3;
        const int gsrc = (lane & 7) ^ srow;

        f32x4 a4[4][4] = {};
        for (int k0 = 0; k0 < 1024; k0 += 64) {
            #pragma unroll
            for (int s = 0; s < 4; ++s) {
                const int rrel = s * 32 + w * 8 + srow;
                gll16(Ain + (long)(bm + rrel) * 1024 + k0 + gsrc * 8,
                      As + (s * 32 + w * 8) * 64);
                gll16(Bin + (long)rrel * 1024 + k0 + gsrc * 8,
                      Bs + (s * 32 + w * 8) * 64);
            }
            __syncthreads();
            #pragma unroll
            for (int st = 0; st < 2; ++st) {
                const int gr = (st * 4 + l4) ^ (l15 & 7);
                short8 a[4], b[4];
                #pragma unroll
                for (int m = 0; m < 4; ++m)
                    a[m] = *(const short8*)&As[(wr * 64 + m * 16 + l15) * 64 + gr * 8];
                #pragma unroll
                for (int n = 0; n < 4; ++n)
                    b[n] = *(const short8*)&Bs[(wc * 64 + n * 16 + l15) * 64 + gr * 8];
                #pragma unroll
                for (int m = 0; m < 4; ++m)
                    #pragma unroll
                    for (int n = 0; n < 4; ++n)
                        a4[m][n] = __builtin_amdgcn_mfma_f32_16x16x32_bf16(a[m], b[n], a4[m][n], 0, 0, 0);
            }
            __syncthreads();
        }
        #pragma unroll
        for (int m = 0; m < 4; ++m) {
            int row = bm + (w >> 1) * 64 + m * 16 + l4 * 4;
            #pragma unroll
            for (int n = 0; n < 4; ++n) {
                int col = (w & 1) * 64 + n * 16 + l15;
                #pragma unroll
                for (int r = 0; r < 4; ++r)
                    Co[(long)(row + r) * 128 + col] = __float2bfloat16(a4[m][n][r]);
            }
        }
        return;
    }

    const int wkid = (bid & 7) * 256 + (bid >> 3);
    const int e = wkid & 15;
    const int b0 = (wkid >> 4) * 64;
    const int cbase = e * 128;
    const int wid = tid >> 6;
    const int side = wid >> 1;
    const int wr = wid & 1;
    const int widthIn = 2048;

    short* h1 = (short*)smem;
    short* Bs = (short*)(smem + 32768);
    float* bins = (float*)(smem + 65536);
    float* b2s  = (float*)(smem + 66048);
    float* w3s  = (float*)(smem + 66560);
    float* red  = (float*)(smem + 67072);

    const short* W2e = W2s + (long)e * 16384;
    #pragma unroll
    for (int l = 0; l < 8; ++l) {
        int cb = (l * 4 + wid) * 64;
        gll16(W2e + (long)(cb + lane) * 8, &Bs[cb * 8]);
    }
    if (tid < 128) {
        bins[tid] = bin[cbase + tid];
        b2s[tid]  = b2[cbase + tid];
        w3s[tid]  = w3[cbase + tid];
    }
    __syncthreads();

    const short* Ys = (const short*)Yp;
    const short* Ms = (const short*)Mq;
    #pragma unroll
    for (int c = 0; c < 4; ++c) {
        int chunk = c * 256 + tid;
        int row = chunk >> 4, kc = chunk & 15;
        short8 yv = *(const short8*)&Ys[(long)(b0 + row) * widthIn + cbase + kc * 8];
        float yf[8];
        #pragma unroll
        for (int j = 0; j < 8; ++j) yf[j] = bf2f(yv[j]) + bins[kc * 8 + j];
        int dst = row * 128 + (kc ^ (row & 7)) * 8;
        #pragma unroll
        for (int s = 0; s < 2; ++s) {
            int rowm = (b0 + row + s) & (B_ROWS - 1);
            short8 mv = *(const short8*)&Ms[(long)rowm * widthIn + cbase + kc * 8];
            union { short8 v; short sh[8]; } o;
            #pragma unroll
            for (int j = 0; j < 8; ++j)
                o.sh[j] = f2bf_s(fmaxf(yf[j] + bf2f(mv[j]), 0.f));
            *(short8*)&h1[s * 8192 + dst] = o.v;
        }
    }
    __syncthreads();

    f32x4 accv[2][8] = {};
    #pragma unroll
    for (int st = 0; st < 4; ++st) {
        short8 a[2], b[8];
        #pragma unroll
        for (int m = 0; m < 2; ++m) {
            int row = wr * 32 + m * 16 + l15;
            int ch = (st * 4 + l4) ^ (row & 7);
            a[m] = *(const short8*)&h1[side * 8192 + row * 128 + ch * 8];
        }
        #pragma unroll
        for (int n = 0; n < 8; ++n) {
            int col = n * 16 + l15;
            int ch = (st * 4 + l4) ^ (col & 7);
            b[n] = *(const short8*)&Bs[col * 128 + ch * 8];
        }
        #pragma unroll
        for (int m = 0; m < 2; ++m)
            #pragma unroll
            for (int n = 0; n < 8; ++n)
                accv[m][n] = __builtin_amdgcn_mfma_f32_16x16x32_bf16(a[m], b[n], accv[m][n], 0, 0, 0);
    }

    float p[2][4] = {};
    #pragma unroll
    for (int m = 0; m < 2; ++m)
        #pragma unroll
        for (int n = 0; n < 8; ++n) {
            int colL = n * 16 + l15;
            float bb = b2s[colL], ww = w3s[colL];
            #pragma unroll
            for (int r = 0; r < 4; ++r) {
                float h2 = fmaxf(accv[m][n][r] + bb, 0.f);
                p[m][r] = fmaf(h2, ww, p[m][r]);
            }
        }
    #pragma unroll
    for (int m = 0; m < 2; ++m)
        #pragma unroll
        for (int r = 0; r < 4; ++r)
            #pragma unroll
            for (int off = 1; off < 16; off <<= 1)
                p[m][r] += __shfl_xor(p[m][r], off, 64);

    float mysum = 0.f;
    if (l15 == 0) {
        float bb = b3[e];
        #pragma unroll
        for (int m = 0; m < 2; ++m)
            #pragma unroll
            for (int r = 0; r < 4; ++r) {
                float s = p[m][r] + bb;
                mysum += softplus_f(side ? s : -s);
            }
    }
    red[tid] = mysum;
    __syncthreads();
    for (int s2 = 128; s2 > 0; s2 >>= 1) {
        if (tid < s2) red[tid] += red[tid + s2];
        __syncthreads();
    }
    if (tid == 0) atomicAdd(acc, (double)red[0]);
}

// ---------- global tail + fused finalize (last-block pattern) --------------
__global__ __launch_bounds__(256) void tail_mfma(
    const __hip_bfloat16* __restrict__ Yp, const __hip_bfloat16* __restrict__ Mq,
    const float* __restrict__ bin,
    const short* __restrict__ W2s,
    const float* __restrict__ b2, const float* __restrict__ w3,
    const float* __restrict__ b3,
    int widthIn, double* __restrict__ acc, int* __restrict__ counter,
    float* __restrict__ out)
{
    const int b0 = blockIdx.x * 64;
    const int e = blockIdx.y;
    const int cbase = e * 128;
    const int tid = threadIdx.x;
    const int lane = tid & 63;
    const int wid = tid >> 6;
    const int side = wid >> 1;
    const int wr = wid & 1;

    __shared__ __align__(16) short h1[2 * 64 * 128];
    __shared__ __align__(16) short Bs[128 * 128];
    __shared__ float bins[128], b2s[128], w3s[128];
    __shared__ float red[256];

    const short* W2e = W2s + (long)e * 16384;
    #pragma unroll
    for (int l = 0; l < 8; ++l) {
        int cb = (l * 4 + wid) * 64;
        gll16(W2e + (long)(cb + lane) * 8, &Bs[cb * 8]);
    }
    if (tid < 128) {
        bins[tid] = bin[cbase + tid];
        b2s[tid]  = b2[cbase + tid];
        w3s[tid]  = w3[cbase + tid];
    }
    __syncthreads();

    const short* Ys = (const short*)Yp;
    const short* Ms = (const short*)Mq;
    #pragma unroll
    for (int c = 0; c < 4; ++c) {
        int chunk = c * 256 + tid;
        int row = chunk >> 4, kc = chunk & 15;
        short8 yv = *(const short8*)&Ys[(long)(b0 + row) * widthIn + cbase + kc * 8];
        float yf[8];
        #pragma unroll
        for (int j = 0; j < 8; ++j) yf[j] = bf2f(yv[j]) + bins[kc * 8 + j];
        int dst = row * 128 + (kc ^ (row & 7)) * 8;
        #pragma unroll
        for (int s = 0; s < 2; ++s) {
            int rowm = (b0 + row + s) & (B_ROWS - 1);
            short8 mv = *(const short8*)&Ms[(long)rowm * widthIn + cbase + kc * 8];
            union { short8 v; short sh[8]; } o;
            #pragma unroll
            for (int j = 0; j < 8; ++j)
                o.sh[j] = f2bf_s(fmaxf(yf[j] + bf2f(mv[j]), 0.f));
            *(short8*)&h1[s * 8192 + dst] = o.v;
        }
    }
    __syncthreads();

    const int l15 = lane & 15, l4 = lane >> 4;
    f32x4 accv[2][8] = {};
    #pragma unroll
    for (int st = 0; st < 4; ++st) {
        short8 a[2], b[8];
        #pragma unroll
        for (int m = 0; m < 2; ++m) {
            int row = wr * 32 + m * 16 + l15;
            int ch = (st * 4 + l4) ^ (row & 7);
            a[m] = *(const short8*)&h1[side * 8192 + row * 128 + ch * 8];
        }
        #pragma unroll
        for (int n = 0; n < 8; ++n) {
            int col = n * 16 + l15;
            int ch = (st * 4 + l4) ^ (col & 7);
            b[n] = *(const short8*)&Bs[col * 128 + ch * 8];
        }
        #pragma unroll
        for (int m = 0; m < 2; ++m)
            #pragma unroll
            for (int n = 0; n < 8; ++n)
                accv[m][n] = __builtin_amdgcn_mfma_f32_16x16x32_bf16(a[m], b[n], accv[m][n], 0, 0, 0);
    }

    float p[2][4] = {};
    #pragma unroll
    for (int m = 0; m < 2; ++m)
        #pragma unroll
        for (int n = 0; n < 8; ++n) {
            int colL = n * 16 + l15;
            float bb = b2s[colL], ww = w3s[colL];
            #pragma unroll
            for (int r = 0; r < 4; ++r) {
                float h2 = fmaxf(accv[m][n][r] + bb, 0.f);
                p[m][r] = fmaf(h2, ww, p[m][r]);
            }
        }
    #pragma unroll
    for (int m = 0; m < 2; ++m)
        #pragma unroll
        for (int r = 0; r < 4; ++r)
            #pragma unroll
            for (int off = 1; off < 16; off <<= 1)
                p[m][r] += __shfl_xor(p[m][r], off, 64);

    float mysum = 0.f;
    if (l15 == 0) {
        float bb = b3[e];
        #pragma unroll
        for (int m = 0; m < 2; ++m)
            #pragma unroll
            for (int r = 0; r < 4; ++r) {
                float s = p[m][r] + bb;
                mysum += softplus_f(side ? s : -s);
            }
    }
    red[tid] = mysum;
    __syncthreads();
    for (int s2 = 128; s2 > 0; s2 >>= 1) {
        if (tid < s2) red[tid] += red[tid + s2];
        __syncthreads();
    }
    if (tid == 0) {
        atomicAdd(acc + 1, (double)red[0]);
        __threadfence();
        int old = atomicAdd(counter, 1);
        if (old == (int)(gridDim.x * gridDim.y) - 1) {
            double a0 = atomicAdd(acc + 0, 0.0);
            double a1 = atomicAdd(acc + 1, 0.0);
            out[0] = (float)(a0 / (8192.0 * 16.0) + 0.5 * a1 / 8192.0);
        }
    }
}

extern "C" void kernel_launch(void* const* d_in, const int* in_sizes, int n_in,
                              void* d_out, int out_size, void* d_ws, size_t ws_size,
                              hipStream_t stream)
{
    const float* y   = (const float*)d_in[0];
    const float* M   = (const float*)d_in[1];
    const float* gw0 = (const float*)d_in[2];
    const float* gb0 = (const float*)d_in[3];
    const float* gw1 = (const float*)d_in[4];
    const float* gb1 = (const float*)d_in[5];
    const float* l0w = (const float*)d_in[6];
    const float* l0b = (const float*)d_in[7];
    const float* l1w = (const float*)d_in[8];
    const float* l1b = (const float*)d_in[9];
    const float* l2w = (const float*)d_in[10];
    const float* l2b = (const float*)d_in[11];
    const float* lW1 = (const float*)d_in[12];
    const float* lb1 = (const float*)d_in[13];
    const float* lW2 = (const float*)d_in[14];
    const float* lb2 = (const float*)d_in[15];
    const float* lW3 = (const float*)d_in[16];
    const float* lb3 = (const float*)d_in[17];

    // ---- workspace layout (~127 MB) ----
    char* w = (char*)d_ws;
    double* acc = (double*)w;
    int* counter = (int*)(w + 16);
    float* bing = (float*)(w + 256);
    const size_t MB = 1u << 20;
    __hip_bfloat16* Y1b  = (__hip_bfloat16*)(w + 4096);             // 32 MB
    __hip_bfloat16* Mpb  = (__hip_bfloat16*)(w + 4096 + 32 * MB);   // 32 MB
    __hip_bfloat16* H0b  = (__hip_bfloat16*)(w + 4096 + 64 * MB);   // 16 MB
    short*          Mt2  = (short*)(w + 4096 + 80 * MB);            // 16 MB
    __hip_bfloat16* yb   = (__hip_bfloat16*)(w + 4096 + 96 * MB);   // 16 MB
    __hip_bfloat16* W1yt = (__hip_bfloat16*)(w + 4096 + 112 * MB);  // 4 MB
    __hip_bfloat16* W0p  = (__hip_bfloat16*)(w + 4096 + 118 * MB);  // 2 MB
    __hip_bfloat16* l0wyt = (__hip_bfloat16*)(w + 4096 + 120 * MB); // 256 KB
    short* W2sb = (short*)(w + 4096 + 120 * MB + 512 * 1024);       // 512 KB
    short* L1ws = (short*)(w + 4096 + 121 * MB);                    // 32 KB
    __hip_bfloat16* WgTb = (__hip_bfloat16*)(w + 4096 + 121 * MB + 512 * 1024); // 256 KB
    short* W1m2 = (short*)(w + 4096 + 122 * MB);                    // 512 KB
    __hip_bfloat16* Tyb = (__hip_bfloat16*)(w + 4096 + 123 * MB);   // 2 MB
    __hip_bfloat16* Tgb = (__hip_bfloat16*)(w + 4096 + 125 * MB);   // 2 MB

    dim3 blk(256);

    prep_all<<<dim3(10074), blk, 0, stream>>>(
        y, M, lW1, gw0, l0w, gb1, l0b, lW2, l1w, gw1,
        yb, Mt2, W1yt, W1m2, W0p, l0wyt, bing, W2sb, L1ws, WgTb,
        acc, counter);

    gemm8ph<<<dim3(640), dim3(512), 0, stream>>>(
        (const short*)yb, (const short*)W1yt, Y1b,
        Mt2, W1m2, Mpb,
        (const short*)W0p, gb0, H0b);

    tail_plus<<<dim3(2176), blk, 0, stream>>>(
        Y1b, Mpb, lb1, W2sb, lb2, lW3, lb3, acc,
        (const short*)H0b, (const short*)WgTb, Tgb,
        (const short*)yb, (const short*)l0wyt, Tyb);

    tail_mfma<<<dim3(128, 1), blk, 0, stream>>>(
        Tyb, Tgb, bing, L1ws, l1b, l2w, l2b, 128, acc, counter,
        (float*)d_out);
}

// Round 4
// 203.543 us; speedup vs baseline: 1.4170x; 1.0454x over previous
//
#include <hip/hip_runtime.h>
#include <hip/hip_bf16.h>
#include <math.h>

#define B_ROWS 8192
#define NEXP 16

typedef __attribute__((ext_vector_type(8))) short short8;
typedef __attribute__((ext_vector_type(4))) float f32x4;

__device__ __forceinline__ float softplus_f(float x) {
    return fmaxf(x, 0.f) + log1pf(expf(-fabsf(x)));
}

__device__ __forceinline__ float bf2f(short u) {
    union { unsigned int i; float f; } c;
    c.i = ((unsigned int)(unsigned short)u) << 16;
    return c.f;
}

__device__ __forceinline__ short f2bf_s(float x) {
    __hip_bfloat16 h = __float2bfloat16(x);
    return *(short*)&h;
}

__device__ __forceinline__ void gll16(const void* g, void* l) {
    __builtin_amdgcn_global_load_lds(
        (const __attribute__((address_space(1))) void*)g,
        (__attribute__((address_space(3))) void*)l, 16, 0, 0);
}

#define FENCE() asm volatile("" ::: "memory")
#define VM8 asm volatile("s_waitcnt vmcnt(8)" ::: "memory")
#define VM4 asm volatile("s_waitcnt vmcnt(4)" ::: "memory")
#define VM0 asm volatile("s_waitcnt vmcnt(0)" ::: "memory")
#define BAR __builtin_amdgcn_s_barrier()

// ================= UBER PREP (all prep roles, ONE launch) ==================
__device__ void cast_body(const float* in, __hip_bfloat16* out, int blk, int tid) {
    int i = blk * 256 + tid;
    float4 v = ((const float4*)in)[i];
    union { ushort4 u; __hip_bfloat16 h[4]; } p;
    p.h[0] = __float2bfloat16(v.x);
    p.h[1] = __float2bfloat16(v.y);
    p.h[2] = __float2bfloat16(v.z);
    p.h[3] = __float2bfloat16(v.w);
    ((ushort4*)out)[i] = p.u;
}

__global__ __launch_bounds__(256) void prep_all(
    const float* __restrict__ y, const float* __restrict__ M,
    const float* __restrict__ lW1, const float* __restrict__ gw0,
    const float* __restrict__ l0w, const float* __restrict__ gb1,
    const float* __restrict__ l0b, const float* __restrict__ lW2,
    const float* __restrict__ l1w, const float* __restrict__ gw1,
    __hip_bfloat16* __restrict__ yb, short* __restrict__ Mt2,
    __hip_bfloat16* __restrict__ W1yt, short* __restrict__ W1m2,
    __hip_bfloat16* __restrict__ W0p, __hip_bfloat16* __restrict__ l0wyt,
    float* __restrict__ bing, short* __restrict__ W2sb,
    short* __restrict__ L1ws, __hip_bfloat16* __restrict__ WgTb,
    double* __restrict__ acc, int* __restrict__ counter)
{
    __shared__ __align__(16) char smem[66048];
    const int b = blockIdx.x;
    const int tid = threadIdx.x;
    const int lane = tid & 63, w = tid >> 6;

    if (b < 8) {
        short* As = (short*)smem;
        short* Bs = (short*)(smem + 16384);
        const int bn = b * 128;
        const int wr = w >> 1, wc = w & 1;
        const int l15 = lane & 15, l4 = lane >> 4;

        f32x4 acc4[4][4] = {};
        for (int k0 = 0; k0 < 1024; k0 += 64) {
            {
                int c4 = (tid & 31) * 4;
                int kkr0 = tid >> 5;
                #pragma unroll
                for (int r = 0; r < 8; ++r) {
                    int kk = r * 8 + kkr0;
                    float4 v = *(const float4*)&l0w[(long)(1024 + k0 + kk) * 128 + c4];
                    int g = kk >> 3, sub = kk & 7;
                    #pragma unroll
                    for (int i = 0; i < 4; ++i) {
                        int row = c4 + i;
                        As[row * 64 + (g ^ (row & 7)) * 8 + sub] = f2bf_s(((const float*)&v)[i]);
                    }
                }
            }
            {
                int jr0 = tid >> 3;
                int g = tid & 7;
                #pragma unroll
                for (int s = 0; s < 4; ++s) {
                    int jrel = s * 32 + jr0;
                    const float* src = &gw1[(long)(bn + jrel) * 1024 + k0 + g * 8];
                    float4 v0 = *(const float4*)src;
                    float4 v1 = *(const float4*)(src + 4);
                    union { short8 v; short sh[8]; } o;
                    o.sh[0] = f2bf_s(v0.x); o.sh[1] = f2bf_s(v0.y);
                    o.sh[2] = f2bf_s(v0.z); o.sh[3] = f2bf_s(v0.w);
                    o.sh[4] = f2bf_s(v1.x); o.sh[5] = f2bf_s(v1.y);
                    o.sh[6] = f2bf_s(v1.z); o.sh[7] = f2bf_s(v1.w);
                    *(short8*)&Bs[jrel * 64 + (g ^ (jrel & 7)) * 8] = o.v;
                }
            }
            __syncthreads();
            #pragma unroll
            for (int st = 0; st < 2; ++st) {
                const int gr = (st * 4 + l4) ^ (l15 & 7);
                short8 a[4], bv[4];
                #pragma unroll
                for (int m = 0; m < 4; ++m)
                    a[m] = *(const short8*)&As[(wr * 64 + m * 16 + l15) * 64 + gr * 8];
                #pragma unroll
                for (int n = 0; n < 4; ++n)
                    bv[n] = *(const short8*)&Bs[(wc * 64 + n * 16 + l15) * 64 + gr * 8];
                #pragma unroll
                for (int m = 0; m < 4; ++m)
                    #pragma unroll
                    for (int n = 0; n < 4; ++n)
                        acc4[m][n] = __builtin_amdgcn_mfma_f32_16x16x32_bf16(a[m], bv[n], acc4[m][n], 0, 0, 0);
            }
            __syncthreads();
        }
        #pragma unroll
        for (int m = 0; m < 4; ++m) {
            int row = wr * 64 + m * 16 + l4 * 4;
            #pragma unroll
            for (int n = 0; n < 4; ++n) {
                int col = bn + wc * 64 + n * 16 + l15;
                #pragma unroll
                for (int r = 0; r < 4; ++r)
                    WgTb[(long)(row + r) * 1024 + col] = __float2bfloat16(acc4[m][n][r]);
            }
        }
        return;
    }

    if (b < 8200) { cast_body(y, yb, b - 8, tid); return; }

    if (b < 9224) {
        short* t = (short*)smem;
        const long r0 = (long)(b - 8200) * 8;
        #pragma unroll
        for (int i = 0; i < 8; ++i) {
            int idx = i * 1024 + tid * 4;
            float4 v = *(const float4*)&M[r0 * 1024 + idx];
            short4 s;
            s.x = f2bf_s(v.x); s.y = f2bf_s(v.y); s.z = f2bf_s(v.z); s.w = f2bf_s(v.w);
            *(short4*)&t[idx] = s;
        }
        __syncthreads();
        const int e = tid & 15, rr = (tid >> 4) & 7, hf = tid >> 7;
        #pragma unroll
        for (int c = 0; c < 4; ++c) {
            union { short8 v; short s[8]; } o;
            #pragma unroll
            for (int j = 0; j < 8; ++j)
                o.s[j] = t[rr * 1024 + (hf * 32 + c * 8 + j) * 16 + e];
            *(short8*)&Mt2[(long)(e >> 1) * (8192L * 128) + (r0 + rr) * 128
                           + (e & 1) * 64 + hf * 32 + c * 8] = o.v;
        }
        return;
    }

    float (*t)[129] = (float(*)[129])smem;

    if (b < 9736) {
        int l = b - 9224, bx = l & 15, by = l >> 4;
        int n0 = bx * 128, k0 = by * 32;
        long base = 64L * 128 + (long)bx * (1088L * 128);
        #pragma unroll
        for (int ll = 0; ll < 16; ++ll) {
            int idx = tid + ll * 256;
            int kk = idx >> 7, nn = idx & 127;
            t[kk][nn] = lW1[base + (long)(k0 + kk) * 128 + nn];
        }
        __syncthreads();
        int nn = tid >> 1, kb = (tid & 1) * 16;
        #pragma unroll
        for (int j = 0; j < 16; ++j)
            W1yt[(long)(n0 + nn) * 1024 + k0 + kb + j] = __float2bfloat16(t[kb + j][nn]);
        return;
    }

    if (b < 9768) {
        int l = b - 9736, bx = l & 15, by = l >> 4;
        int n0 = bx * 128, k0 = by * 32;
        long base = (long)bx * (1088L * 128);
        #pragma unroll
        for (int ll = 0; ll < 16; ++ll) {
            int idx = tid + ll * 256;
            int kk = idx >> 7, nn = idx & 127;
            if (kk < 32) t[kk][nn] = lW1[base + (long)(k0 + kk) * 128 + nn];
        }
        __syncthreads();
        int nn = tid >> 1, kb = (tid & 1) * 16;
        int half = bx & 1;
        #pragma unroll
        for (int j = 0; j < 16; ++j) {
            W1m2[(long)(n0 + nn) * 128 + half * 64 + k0 + kb + j] = f2bf_s(t[kb + j][nn]);
            W1m2[(long)(n0 + nn) * 128 + (1 - half) * 64 + k0 + kb + j] = 0;
        }
        return;
    }

    if (b < 10024) {
        int l = b - 9768, bx = l & 7, by = l >> 3;
        int n0 = bx * 128, k0 = by * 32;
        int e = k0 >> 6, dd0 = k0 & 63;
        #pragma unroll
        for (int ll = 0; ll < 16; ++ll) {
            int idx = tid + ll * 256;
            int kk = idx >> 7, nn = idx & 127;
            t[kk][nn] = gw0[(long)((dd0 + kk) * 16 + e) * 1024 + n0 + nn];
        }
        __syncthreads();
        int nn = tid >> 1, kb = (tid & 1) * 16;
        #pragma unroll
        for (int j = 0; j < 16; ++j)
            W0p[(long)(n0 + nn) * 1024 + k0 + kb + j] = __float2bfloat16(t[kb + j][nn]);
        return;
    }

    if (b < 10056) {
        int by = b - 10024;
        int k0 = by * 32;
        #pragma unroll
        for (int ll = 0; ll < 16; ++ll) {
            int idx = tid + ll * 256;
            int kk = idx >> 7, nn = idx & 127;
            t[kk][nn] = l0w[(long)(k0 + kk) * 128 + nn];
        }
        __syncthreads();
        int nn = tid >> 1, kb = (tid & 1) * 16;
        #pragma unroll
        for (int j = 0; j < 16; ++j)
            l0wyt[(long)nn * 1024 + k0 + kb + j] = __float2bfloat16(t[kb + j][nn]);
        return;
    }

    if (b == 10056) {
        if (tid < 128) {
            float s = l0b[tid];
            for (int o = 0; o < 1024; ++o)
                s = fmaf(gb1[o], l0w[(1024 + o) * 128 + tid], s);
            bing[tid] = s;
        }
        if (tid == 255) { acc[0] = 0.0; acc[1] = 0.0; *counter = 0; }
        return;
    }

    {
        int bb = b - 10057;
        const float* in = (bb < 16) ? lW2 + (long)bb * 16384 : l1w;
        short* out = (bb < 16) ? W2sb + (long)bb * 16384 : L1ws;
        #pragma unroll
        for (int l = 0; l < 64; ++l) {
            int idx = l * 256 + tid;
            t[idx >> 7][idx & 127] = in[idx];
        }
        __syncthreads();
        #pragma unroll
        for (int l = 0; l < 8; ++l) {
            int c = l * 256 + tid;
            int col = c >> 4, kc = c & 15;
            int kcs = kc ^ (col & 7);
            union { short8 v; short s[8]; } u;
            #pragma unroll
            for (int j = 0; j < 8; ++j)
                u.s[j] = f2bf_s(t[kc * 8 + j][col]);
            *(short8*)&out[col * 128 + kcs * 8] = u.v;
        }
    }
}

// ============ GEMM 8-PHASE v2: fixed swizzle + B-register reuse ============
// BM=BN=256, BK=64, 512 thr / 8 waves (2M x 4N), per-wave 128x64, acc[8][4].
// LDS 128 KB: {A,B} x {slot 0,1} x {khalf 0,1} 16 KB regions, layout
// [256 rows x 64 B] with slot = g ^ ((row>>1)&3).
//   Bank math: row stride 64 B alternates bank-halves per row; within a
//   16-lane b128 group, 8 lanes/half x 4 distinct slots ((l15>>1)&3 cycles
//   0..3 twice) = 2 lanes/slot = 2-way = free (m136). R3's (row&3) only hit
//   2 slots -> 4-way -> 6.8M conflict cycles.
// B-frags for a (slot,khalf) are read ONCE (h=0 phase) and held in 16 VGPRs
// across the h=1 phase: 24 ds_read_b128 per K-tile per wave (was 32).
// Phase: ds_reads + 1 half-tile stage (2 gll16/wave) + [vmcnt(8) at even
// phases] + barrier + setprio 16 MFMA + barrier. Region ledger unchanged
// (verified: every region restaged >=1 barrier after its last read; B
// regions now last-read even earlier). Peeled last iter drains 8 -> 4 -> 0.
__global__ __launch_bounds__(512, 2) void gemm8ph(
    const short* __restrict__ yb, const short* __restrict__ W1yt,
    __hip_bfloat16* __restrict__ Y1b,
    const short* __restrict__ Mt2, const short* __restrict__ W1m2,
    __hip_bfloat16* __restrict__ Mpb,
    const short* __restrict__ W0p, const float* __restrict__ gb0,
    __hip_bfloat16* __restrict__ H0b)
{
    __shared__ __align__(16) char smem[131072];
    const int tid = threadIdx.x;
    const int lane = tid & 63, w = tid >> 6;
    const int l15 = lane & 15, l4 = lane >> 4;
    const int wr = w >> 2, wc = w & 3;

    const int bid = blockIdx.x;
    const int xcd = bid & 7;
    const int idx = bid >> 3;

    int grp, bm, bn, K;
    const short* A; const short* Wt; __hip_bfloat16* C; int ldc;
    if (idx < 32) {
        grp = 0; bm = (xcd * 4 + (idx >> 3)) * 256; bn = (idx & 7) * 256;
        A = yb; Wt = W1yt + (long)bn * 1024; K = 1024; C = Y1b; ldc = 2048;
    } else if (idx < 48) {
        int j = idx - 32;
        grp = 2; bm = (xcd * 4 + (j >> 2)) * 256; bn = (j & 3) * 256;
        A = Mt2; Wt = W0p + (long)bn * 1024; K = 1024; C = H0b; ldc = 1024;
    } else {
        int j = idx - 48;
        grp = 1; bm = (xcd * 4 + (j >> 3)) * 256; bn = (j & 7) * 256;
        A = Mt2 + (long)(bn >> 8) * (8192L * 128);
        Wt = W1m2 + (long)bn * 128; K = 128; C = Mpb; ldc = 2048;
    }
    const int nt = K >> 6;

    // staging: lane i -> row sub = i>>2, slot = i&3; source k-group pre-XOR'd
    // with the SAME involution the reader uses: g_src = (lane&3) ^ ((row>>1)&3)
    const int sR = lane >> 2;
    const int sG = (lane & 3) ^ ((sR >> 1) & 3);

    auto STAGE_A = [&](int s, int k, int t) {
        #pragma unroll
        for (int blk = 0; blk < 2; ++blk) {
            const int row = w * 32 + blk * 16 + sR;
            const short* src;
            if (grp == 2) {
                const int g = t * 8 + k * 4 + sG;
                src = A + (long)(g >> 4) * (8192L * 128)
                        + (long)(bm + row) * 128 + (g & 15) * 8;
            } else {
                src = A + (long)(bm + row) * K + t * 64 + k * 32 + sG * 8;
            }
            gll16(src, smem + s * 32768 + k * 16384 + w * 2048 + blk * 1024);
        }
    };
    auto STAGE_B = [&](int s, int k, int t) {
        #pragma unroll
        for (int blk = 0; blk < 2; ++blk) {
            const int row = w * 32 + blk * 16 + sR;
            gll16(Wt + (long)row * K + t * 64 + k * 32 + sG * 8,
                  smem + 65536 + s * 32768 + k * 16384 + w * 2048 + blk * 1024);
        }
    };

    f32x4 acc[8][4] = {};
    short8 b_[4];   // B fragments held across the two m-half phases
    const int xr = (l4 ^ ((l15 >> 1) & 3)) * 16;
    const int aOff = (wr * 128 + l15) * 64 + xr;
    const int bOff = (wc * 64 + l15) * 64 + xr;

// RDB=1: load b_ from LDS (h=0 phase); RDB=0: reuse b_ regs (h=1 phase)
#define PHASE(s, k, h, RDB, STG, WT) do {                                     \
    short8 a_[4];                                                             \
    const int RO = (s) * 32768 + (k) * 16384;                                 \
    _Pragma("unroll")                                                         \
    for (int mm = 0; mm < 4; ++mm)                                            \
        a_[mm] = *(const short8*)(smem + RO + aOff + (h) * 4096 + mm * 1024); \
    if (RDB) {                                                                \
        _Pragma("unroll")                                                     \
        for (int n = 0; n < 4; ++n)                                           \
            b_[n] = *(const short8*)(smem + 65536 + RO + bOff + n * 1024);    \
    }                                                                         \
    STG; WT; FENCE(); BAR; FENCE();                                           \
    __builtin_amdgcn_s_setprio(1);                                            \
    _Pragma("unroll")                                                         \
    for (int mm = 0; mm < 4; ++mm)                                            \
        _Pragma("unroll")                                                     \
        for (int n = 0; n < 4; ++n)                                           \
            acc[(h) * 4 + mm][n] = __builtin_amdgcn_mfma_f32_16x16x32_bf16(   \
                a_[mm], b_[n], acc[(h) * 4 + mm][n], 0, 0, 0);                \
    __builtin_amdgcn_s_setprio(0);                                            \
    FENCE(); BAR; FENCE();                                                    \
} while (0)

    // prologue: tile0 (k0,k1) + tile1 (k0) = 12 loads; vmcnt(8) -> (0,k0) in
    STAGE_A(0, 0, 0); STAGE_B(0, 0, 0);
    STAGE_A(0, 1, 0); STAGE_B(0, 1, 0);
    STAGE_A(1, 0, 1); STAGE_B(1, 0, 1);
    VM8; FENCE(); BAR; FENCE();

    const int ni = nt >> 1;
    for (int i = 0; i < ni - 1; ++i) {
        const int T0 = i * 2;
        PHASE(0, 0, 0, 1, STAGE_A(1, 1, T0 + 1), {});
        PHASE(0, 0, 1, 0, STAGE_B(1, 1, T0 + 1), VM8);
        PHASE(0, 1, 0, 1, STAGE_A(0, 0, T0 + 2), {});
        PHASE(0, 1, 1, 0, STAGE_B(0, 0, T0 + 2), VM8);
        PHASE(1, 0, 0, 1, STAGE_A(0, 1, T0 + 2), {});
        PHASE(1, 0, 1, 0, STAGE_B(0, 1, T0 + 2), VM8);
        PHASE(1, 1, 0, 1, STAGE_A(1, 0, T0 + 3), {});
        PHASE(1, 1, 1, 0, STAGE_B(1, 0, T0 + 3), VM8);
    }
    {   // peeled last iteration (tiles nt-2, nt-1): drain 8 -> 4 -> 0
        const int T0 = nt - 2;
        PHASE(0, 0, 0, 1, STAGE_A(1, 1, T0 + 1), {});
        PHASE(0, 0, 1, 0, STAGE_B(1, 1, T0 + 1), VM8);
        PHASE(0, 1, 0, 1, {}, {});
        PHASE(0, 1, 1, 0, {}, VM4);
        PHASE(1, 0, 0, 1, {}, {});
        PHASE(1, 0, 1, 0, {}, VM0);
        PHASE(1, 1, 0, 1, {}, {});
        PHASE(1, 1, 1, 0, {}, {});
    }
#undef PHASE

    #pragma unroll
    for (int m = 0; m < 8; ++m) {
        const int row = bm + wr * 128 + m * 16 + l4 * 4;
        #pragma unroll
        for (int n = 0; n < 4; ++n) {
            const int col = bn + wc * 64 + n * 16 + l15;
            const float bv = (grp == 2) ? gb0[col] : 0.f;
            #pragma unroll
            for (int r = 0; r < 4; ++r) {
                float v = acc[m][n][r] + bv;
                if (grp == 2) v = fmaxf(v, 0.f);
                C[(long)(row + r) * ldc + col] = __float2bfloat16(v);
            }
        }
    }
}

// ===== tail_plus: [0,2048) local tail (XCD-swz), [2048,2112) Tg GEMM,
//                  [2112,2176) Ty GEMM (grp3, moved out of the mega GEMM) ===
__global__ __launch_bounds__(256) void tail_plus(
    const __hip_bfloat16* __restrict__ Yp, const __hip_bfloat16* __restrict__ Mq,
    const float* __restrict__ bin, const short* __restrict__ W2s,
    const float* __restrict__ b2, const float* __restrict__ w3,
    const float* __restrict__ b3, double* __restrict__ acc,
    const short* __restrict__ H0b, const short* __restrict__ WgTb,
    __hip_bfloat16* __restrict__ Tgb,
    const short* __restrict__ ybs, const short* __restrict__ l0ws,
    __hip_bfloat16* __restrict__ Tyb)
{
    __shared__ __align__(16) char smem[68096];
    const int bid = blockIdx.x;
    const int tid = threadIdx.x;
    const int lane = tid & 63;
    const int l15 = lane & 15, l4 = lane >> 4;

    if (bid >= 2048) {
        const int sel = bid - 2048;
        const short* Ain = (sel < 64) ? H0b : ybs;
        const short* Bin = (sel < 64) ? WgTb : l0ws;
        __hip_bfloat16* Co = (sel < 64) ? Tgb : Tyb;
        short* As = (short*)smem;
        short* Bs = (short*)(smem + 16384);
        const int w = tid >> 6;
        const int wr = w >> 1, wc = w & 1;
        const int bm = (sel & 63) * 128;
        const int srow = lane >> 3;
        const int gsrc = (lane & 7) ^ srow;

        f32x4 a4[4][4] = {};
        for (int k0 = 0; k0 < 1024; k0 += 64) {
            #pragma unroll
            for (int s = 0; s < 4; ++s) {
                const int rrel = s * 32 + w * 8 + srow;
                gll16(Ain + (long)(bm + rrel) * 1024 + k0 + gsrc * 8,
                      As + (s * 32 + w * 8) * 64);
                gll16(Bin + (long)rrel * 1024 + k0 + gsrc * 8,
                      Bs + (s * 32 + w * 8) * 64);
            }
            __syncthreads();
            #pragma unroll
            for (int st = 0; st < 2; ++st) {
                const int gr = (st * 4 + l4) ^ (l15 & 7);
                short8 a[4], b[4];
                #pragma unroll
                for (int m = 0; m < 4; ++m)
                    a[m] = *(const short8*)&As[(wr * 64 + m * 16 + l15) * 64 + gr * 8];
                #pragma unroll
                for (int n = 0; n < 4; ++n)
                    b[n] = *(const short8*)&Bs[(wc * 64 + n * 16 + l15) * 64 + gr * 8];
                #pragma unroll
                for (int m = 0; m < 4; ++m)
                    #pragma unroll
                    for (int n = 0; n < 4; ++n)
                        a4[m][n] = __builtin_amdgcn_mfma_f32_16x16x32_bf16(a[m], b[n], a4[m][n], 0, 0, 0);
            }
            __syncthreads();
        }
        #pragma unroll
        for (int m = 0; m < 4; ++m) {
            int row = bm + (w >> 1) * 64 + m * 16 + l4 * 4;
            #pragma unroll
            for (int n = 0; n < 4; ++n) {
                int col = (w & 1) * 64 + n * 16 + l15;
                #pragma unroll
                for (int r = 0; r < 4; ++r)
                    Co[(long)(row + r) * 128 + col] = __float2bfloat16(a4[m][n][r]);
            }
        }
        return;
    }

    const int wkid = (bid & 7) * 256 + (bid >> 3);
    const int e = wkid & 15;
    const int b0 = (wkid >> 4) * 64;
    const int cbase = e * 128;
    const int wid = tid >> 6;
    const int side = wid >> 1;
    const int wr = wid & 1;
    const int widthIn = 2048;

    short* h1 = (short*)smem;
    short* Bs = (short*)(smem + 32768);
    float* bins = (float*)(smem + 65536);
    float* b2s  = (float*)(smem + 66048);
    float* w3s  = (float*)(smem + 66560);
    float* red  = (float*)(smem + 67072);

    const short* W2e = W2s + (long)e * 16384;
    #pragma unroll
    for (int l = 0; l < 8; ++l) {
        int cb = (l * 4 + wid) * 64;
        gll16(W2e + (long)(cb + lane) * 8, &Bs[cb * 8]);
    }
    if (tid < 128) {
        bins[tid] = bin[cbase + tid];
        b2s[tid]  = b2[cbase + tid];
        w3s[tid]  = w3[cbase + tid];
    }
    __syncthreads();

    const short* Ys = (const short*)Yp;
    const short* Ms = (const short*)Mq;
    #pragma unroll
    for (int c = 0; c < 4; ++c) {
        int chunk = c * 256 + tid;
        int row = chunk >> 4, kc = chunk & 15;
        short8 yv = *(const short8*)&Ys[(long)(b0 + row) * widthIn + cbase + kc * 8];
        float yf[8];
        #pragma unroll
        for (int j = 0; j < 8; ++j) yf[j] = bf2f(yv[j]) + bins[kc * 8 + j];
        int dst = row * 128 + (kc ^ (row & 7)) * 8;
        #pragma unroll
        for (int s = 0; s < 2; ++s) {
            int rowm = (b0 + row + s) & (B_ROWS - 1);
            short8 mv = *(const short8*)&Ms[(long)rowm * widthIn + cbase + kc * 8];
            union { short8 v; short sh[8]; } o;
            #pragma unroll
            for (int j = 0; j < 8; ++j)
                o.sh[j] = f2bf_s(fmaxf(yf[j] + bf2f(mv[j]), 0.f));
            *(short8*)&h1[s * 8192 + dst] = o.v;
        }
    }
    __syncthreads();

    f32x4 accv[2][8] = {};
    #pragma unroll
    for (int st = 0; st < 4; ++st) {
        short8 a[2], b[8];
        #pragma unroll
        for (int m = 0; m < 2; ++m) {
            int row = wr * 32 + m * 16 + l15;
            int ch = (st * 4 + l4) ^ (row & 7);
            a[m] = *(const short8*)&h1[side * 8192 + row * 128 + ch * 8];
        }
        #pragma unroll
        for (int n = 0; n < 8; ++n) {
            int col = n * 16 + l15;
            int ch = (st * 4 + l4) ^ (col & 7);
            b[n] = *(const short8*)&Bs[col * 128 + ch * 8];
        }
        #pragma unroll
        for (int m = 0; m < 2; ++m)
            #pragma unroll
            for (int n = 0; n < 8; ++n)
                accv[m][n] = __builtin_amdgcn_mfma_f32_16x16x32_bf16(a[m], b[n], accv[m][n], 0, 0, 0);
    }

    float p[2][4] = {};
    #pragma unroll
    for (int m = 0; m < 2; ++m)
        #pragma unroll
        for (int n = 0; n < 8; ++n) {
            int colL = n * 16 + l15;
            float bb = b2s[colL], ww = w3s[colL];
            #pragma unroll
            for (int r = 0; r < 4; ++r) {
                float h2 = fmaxf(accv[m][n][r] + bb, 0.f);
                p[m][r] = fmaf(h2, ww, p[m][r]);
            }
        }
    #pragma unroll
    for (int m = 0; m < 2; ++m)
        #pragma unroll
        for (int r = 0; r < 4; ++r)
            #pragma unroll
            for (int off = 1; off < 16; off <<= 1)
                p[m][r] += __shfl_xor(p[m][r], off, 64);

    float mysum = 0.f;
    if (l15 == 0) {
        float bb = b3[e];
        #pragma unroll
        for (int m = 0; m < 2; ++m)
            #pragma unroll
            for (int r = 0; r < 4; ++r) {
                float s = p[m][r] + bb;
                mysum += softplus_f(side ? s : -s);
            }
    }
    red[tid] = mysum;
    __syncthreads();
    for (int s2 = 128; s2 > 0; s2 >>= 1) {
        if (tid < s2) red[tid] += red[tid + s2];
        __syncthreads();
    }
    if (tid == 0) atomicAdd(acc, (double)red[0]);
}

// ---------- global tail + fused finalize (last-block pattern) --------------
__global__ __launch_bounds__(256) void tail_mfma(
    const __hip_bfloat16* __restrict__ Yp, const __hip_bfloat16* __restrict__ Mq,
    const float* __restrict__ bin,
    const short* __restrict__ W2s,
    const float* __restrict__ b2, const float* __restrict__ w3,
    const float* __restrict__ b3,
    int widthIn, double* __restrict__ acc, int* __restrict__ counter,
    float* __restrict__ out)
{
    const int b0 = blockIdx.x * 64;
    const int e = blockIdx.y;
    const int cbase = e * 128;
    const int tid = threadIdx.x;
    const int lane = tid & 63;
    const int wid = tid >> 6;
    const int side = wid >> 1;
    const int wr = wid & 1;

    __shared__ __align__(16) short h1[2 * 64 * 128];
    __shared__ __align__(16) short Bs[128 * 128];
    __shared__ float bins[128], b2s[128], w3s[128];
    __shared__ float red[256];

    const short* W2e = W2s + (long)e * 16384;
    #pragma unroll
    for (int l = 0; l < 8; ++l) {
        int cb = (l * 4 + wid) * 64;
        gll16(W2e + (long)(cb + lane) * 8, &Bs[cb * 8]);
    }
    if (tid < 128) {
        bins[tid] = bin[cbase + tid];
        b2s[tid]  = b2[cbase + tid];
        w3s[tid]  = w3[cbase + tid];
    }
    __syncthreads();

    const short* Ys = (const short*)Yp;
    const short* Ms = (const short*)Mq;
    #pragma unroll
    for (int c = 0; c < 4; ++c) {
        int chunk = c * 256 + tid;
        int row = chunk >> 4, kc = chunk & 15;
        short8 yv = *(const short8*)&Ys[(long)(b0 + row) * widthIn + cbase + kc * 8];
        float yf[8];
        #pragma unroll
        for (int j = 0; j < 8; ++j) yf[j] = bf2f(yv[j]) + bins[kc * 8 + j];
        int dst = row * 128 + (kc ^ (row & 7)) * 8;
        #pragma unroll
        for (int s = 0; s < 2; ++s) {
            int rowm = (b0 + row + s) & (B_ROWS - 1);
            short8 mv = *(const short8*)&Ms[(long)rowm * widthIn + cbase + kc * 8];
            union { short8 v; short sh[8]; } o;
            #pragma unroll
            for (int j = 0; j < 8; ++j)
                o.sh[j] = f2bf_s(fmaxf(yf[j] + bf2f(mv[j]), 0.f));
            *(short8*)&h1[s * 8192 + dst] = o.v;
        }
    }
    __syncthreads();

    const int l15 = lane & 15, l4 = lane >> 4;
    f32x4 accv[2][8] = {};
    #pragma unroll
    for (int st = 0; st < 4; ++st) {
        short8 a[2], b[8];
        #pragma unroll
        for (int m = 0; m < 2; ++m) {
            int row = wr * 32 + m * 16 + l15;
            int ch = (st * 4 + l4) ^ (row & 7);
            a[m] = *(const short8*)&h1[side * 8192 + row * 128 + ch * 8];
        }
        #pragma unroll
        for (int n = 0; n < 8; ++n) {
            int col = n * 16 + l15;
            int ch = (st * 4 + l4) ^ (col & 7);
            b[n] = *(const short8*)&Bs[col * 128 + ch * 8];
        }
        #pragma unroll
        for (int m = 0; m < 2; ++m)
            #pragma unroll
            for (int n = 0; n < 8; ++n)
                accv[m][n] = __builtin_amdgcn_mfma_f32_16x16x32_bf16(a[m], b[n], accv[m][n], 0, 0, 0);
    }

    float p[2][4] = {};
    #pragma unroll
    for (int m = 0; m < 2; ++m)
        #pragma unroll
        for (int n = 0; n < 8; ++n) {
            int colL = n * 16 + l15;
            float bb = b2s[colL], ww = w3s[colL];
            #pragma unroll
            for (int r = 0; r < 4; ++r) {
                float h2 = fmaxf(accv[m][n][r] + bb, 0.f);
                p[m][r] = fmaf(h2, ww, p[m][r]);
            }
        }
    #pragma unroll
    for (int m = 0; m < 2; ++m)
        #pragma unroll
        for (int r = 0; r < 4; ++r)
            #pragma unroll
            for (int off = 1; off < 16; off <<= 1)
                p[m][r] += __shfl_xor(p[m][r], off, 64);

    float mysum = 0.f;
    if (l15 == 0) {
        float bb = b3[e];
        #pragma unroll
        for (int m = 0; m < 2; ++m)
            #pragma unroll
            for (int r = 0; r < 4; ++r) {
                float s = p[m][r] + bb;
                mysum += softplus_f(side ? s : -s);
            }
    }
    red[tid] = mysum;
    __syncthreads();
    for (int s2 = 128; s2 > 0; s2 >>= 1) {
        if (tid < s2) red[tid] += red[tid + s2];
        __syncthreads();
    }
    if (tid == 0) {
        atomicAdd(acc + 1, (double)red[0]);
        __threadfence();
        int old = atomicAdd(counter, 1);
        if (old == (int)(gridDim.x * gridDim.y) - 1) {
            double a0 = atomicAdd(acc + 0, 0.0);
            double a1 = atomicAdd(acc + 1, 0.0);
            out[0] = (float)(a0 / (8192.0 * 16.0) + 0.5 * a1 / 8192.0);
        }
    }
}

extern "C" void kernel_launch(void* const* d_in, const int* in_sizes, int n_in,
                              void* d_out, int out_size, void* d_ws, size_t ws_size,
                              hipStream_t stream)
{
    const float* y   = (const float*)d_in[0];
    const float* M   = (const float*)d_in[1];
    const float* gw0 = (const float*)d_in[2];
    const float* gb0 = (const float*)d_in[3];
    const float* gw1 = (const float*)d_in[4];
    const float* gb1 = (const float*)d_in[5];
    const float* l0w = (const float*)d_in[6];
    const float* l0b = (const float*)d_in[7];
    const float* l1w = (const float*)d_in[8];
    const float* l1b = (const float*)d_in[9];
    const float* l2w = (const float*)d_in[10];
    const float* l2b = (const float*)d_in[11];
    const float* lW1 = (const float*)d_in[12];
    const float* lb1 = (const float*)d_in[13];
    const float* lW2 = (const float*)d_in[14];
    const float* lb2 = (const float*)d_in[15];
    const float* lW3 = (const float*)d_in[16];
    const float* lb3 = (const float*)d_in[17];

    // ---- workspace layout (~127 MB) ----
    char* w = (char*)d_ws;
    double* acc = (double*)w;
    int* counter = (int*)(w + 16);
    float* bing = (float*)(w + 256);
    const size_t MB = 1u << 20;
    __hip_bfloat16* Y1b  = (__hip_bfloat16*)(w + 4096);             // 32 MB
    __hip_bfloat16* Mpb  = (__hip_bfloat16*)(w + 4096 + 32 * MB);   // 32 MB
    __hip_bfloat16* H0b  = (__hip_bfloat16*)(w + 4096 + 64 * MB);   // 16 MB
    short*          Mt2  = (short*)(w + 4096 + 80 * MB);            // 16 MB
    __hip_bfloat16* yb   = (__hip_bfloat16*)(w + 4096 + 96 * MB);   // 16 MB
    __hip_bfloat16* W1yt = (__hip_bfloat16*)(w + 4096 + 112 * MB);  // 4 MB
    __hip_bfloat16* W0p  = (__hip_bfloat16*)(w + 4096 + 118 * MB);  // 2 MB
    __hip_bfloat16* l0wyt = (__hip_bfloat16*)(w + 4096 + 120 * MB); // 256 KB
    short* W2sb = (short*)(w + 4096 + 120 * MB + 512 * 1024);       // 512 KB
    short* L1ws = (short*)(w + 4096 + 121 * MB);                    // 32 KB
    __hip_bfloat16* WgTb = (__hip_bfloat16*)(w + 4096 + 121 * MB + 512 * 1024); // 256 KB
    short* W1m2 = (short*)(w + 4096 + 122 * MB);                    // 512 KB
    __hip_bfloat16* Tyb = (__hip_bfloat16*)(w + 4096 + 123 * MB);   // 2 MB
    __hip_bfloat16* Tgb = (__hip_bfloat16*)(w + 4096 + 125 * MB);   // 2 MB

    dim3 blk(256);

    prep_all<<<dim3(10074), blk, 0, stream>>>(
        y, M, lW1, gw0, l0w, gb1, l0b, lW2, l1w, gw1,
        yb, Mt2, W1yt, W1m2, W0p, l0wyt, bing, W2sb, L1ws, WgTb,
        acc, counter);

    gemm8ph<<<dim3(640), dim3(512), 0, stream>>>(
        (const short*)yb, (const short*)W1yt, Y1b,
        Mt2, W1m2, Mpb,
        (const short*)W0p, gb0, H0b);

    tail_plus<<<dim3(2176), blk, 0, stream>>>(
        Y1b, Mpb, lb1, W2sb, lb2, lW3, lb3, acc,
        (const short*)H0b, (const short*)WgTb, Tgb,
        (const short*)yb, (const short*)l0wyt, Tyb);

    tail_mfma<<<dim3(128, 1), blk, 0, stream>>>(
        Tyb, Tgb, bing, L1ws, l1b, l2w, l2b, 128, acc, counter,
        (float*)d_out);
}

// Round 5
// 196.648 us; speedup vs baseline: 1.4667x; 1.0351x over previous
//
#include <hip/hip_runtime.h>
#include <hip/hip_bf16.h>
#include <math.h>

#define B_ROWS 8192
#define NEXP 16

typedef __attribute__((ext_vector_type(8))) short short8;
typedef __attribute__((ext_vector_type(4))) float f32x4;

__device__ __forceinline__ float softplus_f(float x) {
    return fmaxf(x, 0.f) + log1pf(expf(-fabsf(x)));
}

__device__ __forceinline__ float bf2f(short u) {
    union { unsigned int i; float f; } c;
    c.i = ((unsigned int)(unsigned short)u) << 16;
    return c.f;
}

__device__ __forceinline__ short f2bf_s(float x) {
    __hip_bfloat16 h = __float2bfloat16(x);
    return *(short*)&h;
}

__device__ __forceinline__ void gll16(const void* g, void* l) {
    __builtin_amdgcn_global_load_lds(
        (const __attribute__((address_space(1))) void*)g,
        (__attribute__((address_space(3))) void*)l, 16, 0, 0);
}

#define FENCE() asm volatile("" ::: "memory")
#define VM3 asm volatile("s_waitcnt vmcnt(3)" ::: "memory")
#define VM0 asm volatile("s_waitcnt vmcnt(0)" ::: "memory")
#define BAR __builtin_amdgcn_s_barrier()

// ================= UBER PREP (all prep roles, ONE launch) ==================
__device__ void cast_body(const float* in, __hip_bfloat16* out, int blk, int tid) {
    int i = blk * 256 + tid;
    float4 v = ((const float4*)in)[i];
    union { ushort4 u; __hip_bfloat16 h[4]; } p;
    p.h[0] = __float2bfloat16(v.x);
    p.h[1] = __float2bfloat16(v.y);
    p.h[2] = __float2bfloat16(v.z);
    p.h[3] = __float2bfloat16(v.w);
    ((ushort4*)out)[i] = p.u;
}

__global__ __launch_bounds__(256) void prep_all(
    const float* __restrict__ y, const float* __restrict__ M,
    const float* __restrict__ lW1, const float* __restrict__ gw0,
    const float* __restrict__ l0w, const float* __restrict__ gb1,
    const float* __restrict__ l0b, const float* __restrict__ lW2,
    const float* __restrict__ l1w, const float* __restrict__ gw1,
    __hip_bfloat16* __restrict__ yb, short* __restrict__ Mt2,
    __hip_bfloat16* __restrict__ W1yt, short* __restrict__ W1m2,
    __hip_bfloat16* __restrict__ W0p, __hip_bfloat16* __restrict__ l0wyt,
    float* __restrict__ bing, short* __restrict__ W2sb,
    short* __restrict__ L1ws, __hip_bfloat16* __restrict__ WgTb,
    double* __restrict__ acc, int* __restrict__ counter)
{
    __shared__ __align__(16) char smem[66048];
    const int b = blockIdx.x;
    const int tid = threadIdx.x;
    const int lane = tid & 63, w = tid >> 6;

    if (b < 8) {
        short* As = (short*)smem;
        short* Bs = (short*)(smem + 16384);
        const int bn = b * 128;
        const int wr = w >> 1, wc = w & 1;
        const int l15 = lane & 15, l4 = lane >> 4;

        f32x4 acc4[4][4] = {};
        for (int k0 = 0; k0 < 1024; k0 += 64) {
            {
                int c4 = (tid & 31) * 4;
                int kkr0 = tid >> 5;
                #pragma unroll
                for (int r = 0; r < 8; ++r) {
                    int kk = r * 8 + kkr0;
                    float4 v = *(const float4*)&l0w[(long)(1024 + k0 + kk) * 128 + c4];
                    int g = kk >> 3, sub = kk & 7;
                    #pragma unroll
                    for (int i = 0; i < 4; ++i) {
                        int row = c4 + i;
                        As[row * 64 + (g ^ (row & 7)) * 8 + sub] = f2bf_s(((const float*)&v)[i]);
                    }
                }
            }
            {
                int jr0 = tid >> 3;
                int g = tid & 7;
                #pragma unroll
                for (int s = 0; s < 4; ++s) {
                    int jrel = s * 32 + jr0;
                    const float* src = &gw1[(long)(bn + jrel) * 1024 + k0 + g * 8];
                    float4 v0 = *(const float4*)src;
                    float4 v1 = *(const float4*)(src + 4);
                    union { short8 v; short sh[8]; } o;
                    o.sh[0] = f2bf_s(v0.x); o.sh[1] = f2bf_s(v0.y);
                    o.sh[2] = f2bf_s(v0.z); o.sh[3] = f2bf_s(v0.w);
                    o.sh[4] = f2bf_s(v1.x); o.sh[5] = f2bf_s(v1.y);
                    o.sh[6] = f2bf_s(v1.z); o.sh[7] = f2bf_s(v1.w);
                    *(short8*)&Bs[jrel * 64 + (g ^ (jrel & 7)) * 8] = o.v;
                }
            }
            __syncthreads();
            #pragma unroll
            for (int st = 0; st < 2; ++st) {
                const int gr = (st * 4 + l4) ^ (l15 & 7);
                short8 a[4], bv[4];
                #pragma unroll
                for (int m = 0; m < 4; ++m)
                    a[m] = *(const short8*)&As[(wr * 64 + m * 16 + l15) * 64 + gr * 8];
                #pragma unroll
                for (int n = 0; n < 4; ++n)
                    bv[n] = *(const short8*)&Bs[(wc * 64 + n * 16 + l15) * 64 + gr * 8];
                #pragma unroll
                for (int m = 0; m < 4; ++m)
                    #pragma unroll
                    for (int n = 0; n < 4; ++n)
                        acc4[m][n] = __builtin_amdgcn_mfma_f32_16x16x32_bf16(a[m], bv[n], acc4[m][n], 0, 0, 0);
            }
            __syncthreads();
        }
        #pragma unroll
        for (int m = 0; m < 4; ++m) {
            int row = wr * 64 + m * 16 + l4 * 4;
            #pragma unroll
            for (int n = 0; n < 4; ++n) {
                int col = bn + wc * 64 + n * 16 + l15;
                #pragma unroll
                for (int r = 0; r < 4; ++r)
                    WgTb[(long)(row + r) * 1024 + col] = __float2bfloat16(acc4[m][n][r]);
            }
        }
        return;
    }

    if (b < 8200) { cast_body(y, yb, b - 8, tid); return; }

    if (b < 9224) {
        short* t = (short*)smem;
        const long r0 = (long)(b - 8200) * 8;
        #pragma unroll
        for (int i = 0; i < 8; ++i) {
            int idx = i * 1024 + tid * 4;
            float4 v = *(const float4*)&M[r0 * 1024 + idx];
            short4 s;
            s.x = f2bf_s(v.x); s.y = f2bf_s(v.y); s.z = f2bf_s(v.z); s.w = f2bf_s(v.w);
            *(short4*)&t[idx] = s;
        }
        __syncthreads();
        const int e = tid & 15, rr = (tid >> 4) & 7, hf = tid >> 7;
        #pragma unroll
        for (int c = 0; c < 4; ++c) {
            union { short8 v; short s[8]; } o;
            #pragma unroll
            for (int j = 0; j < 8; ++j)
                o.s[j] = t[rr * 1024 + (hf * 32 + c * 8 + j) * 16 + e];
            *(short8*)&Mt2[(long)(e >> 1) * (8192L * 128) + (r0 + rr) * 128
                           + (e & 1) * 64 + hf * 32 + c * 8] = o.v;
        }
        return;
    }

    float (*t)[129] = (float(*)[129])smem;

    if (b < 9736) {
        int l = b - 9224, bx = l & 15, by = l >> 4;
        int n0 = bx * 128, k0 = by * 32;
        long base = 64L * 128 + (long)bx * (1088L * 128);
        #pragma unroll
        for (int ll = 0; ll < 16; ++ll) {
            int idx = tid + ll * 256;
            int kk = idx >> 7, nn = idx & 127;
            t[kk][nn] = lW1[base + (long)(k0 + kk) * 128 + nn];
        }
        __syncthreads();
        int nn = tid >> 1, kb = (tid & 1) * 16;
        #pragma unroll
        for (int j = 0; j < 16; ++j)
            W1yt[(long)(n0 + nn) * 1024 + k0 + kb + j] = __float2bfloat16(t[kb + j][nn]);
        return;
    }

    if (b < 9768) {
        int l = b - 9736, bx = l & 15, by = l >> 4;
        int n0 = bx * 128, k0 = by * 32;
        long base = (long)bx * (1088L * 128);
        #pragma unroll
        for (int ll = 0; ll < 16; ++ll) {
            int idx = tid + ll * 256;
            int kk = idx >> 7, nn = idx & 127;
            if (kk < 32) t[kk][nn] = lW1[base + (long)(k0 + kk) * 128 + nn];
        }
        __syncthreads();
        int nn = tid >> 1, kb = (tid & 1) * 16;
        int half = bx & 1;
        #pragma unroll
        for (int j = 0; j < 16; ++j) {
            W1m2[(long)(n0 + nn) * 128 + half * 64 + k0 + kb + j] = f2bf_s(t[kb + j][nn]);
            W1m2[(long)(n0 + nn) * 128 + (1 - half) * 64 + k0 + kb + j] = 0;
        }
        return;
    }

    if (b < 10024) {
        int l = b - 9768, bx = l & 7, by = l >> 3;
        int n0 = bx * 128, k0 = by * 32;
        int e = k0 >> 6, dd0 = k0 & 63;
        #pragma unroll
        for (int ll = 0; ll < 16; ++ll) {
            int idx = tid + ll * 256;
            int kk = idx >> 7, nn = idx & 127;
            t[kk][nn] = gw0[(long)((dd0 + kk) * 16 + e) * 1024 + n0 + nn];
        }
        __syncthreads();
        int nn = tid >> 1, kb = (tid & 1) * 16;
        #pragma unroll
        for (int j = 0; j < 16; ++j)
            W0p[(long)(n0 + nn) * 1024 + k0 + kb + j] = __float2bfloat16(t[kb + j][nn]);
        return;
    }

    if (b < 10056) {
        int by = b - 10024;
        int k0 = by * 32;
        #pragma unroll
        for (int ll = 0; ll < 16; ++ll) {
            int idx = tid + ll * 256;
            int kk = idx >> 7, nn = idx & 127;
            t[kk][nn] = l0w[(long)(k0 + kk) * 128 + nn];
        }
        __syncthreads();
        int nn = tid >> 1, kb = (tid & 1) * 16;
        #pragma unroll
        for (int j = 0; j < 16; ++j)
            l0wyt[(long)nn * 1024 + k0 + kb + j] = __float2bfloat16(t[kb + j][nn]);
        return;
    }

    if (b == 10056) {
        if (tid < 128) {
            float s = l0b[tid];
            for (int o = 0; o < 1024; ++o)
                s = fmaf(gb1[o], l0w[(1024 + o) * 128 + tid], s);
            bing[tid] = s;
        }
        if (tid == 255) { acc[0] = 0.0; acc[1] = 0.0; *counter = 0; }
        return;
    }

    {
        int bb = b - 10057;
        const float* in = (bb < 16) ? lW2 + (long)bb * 16384 : l1w;
        short* out = (bb < 16) ? W2sb + (long)bb * 16384 : L1ws;
        #pragma unroll
        for (int l = 0; l < 64; ++l) {
            int idx = l * 256 + tid;
            t[idx >> 7][idx & 127] = in[idx];
        }
        __syncthreads();
        #pragma unroll
        for (int l = 0; l < 8; ++l) {
            int c = l * 256 + tid;
            int col = c >> 4, kc = c & 15;
            int kcs = kc ^ (col & 7);
            union { short8 v; short s[8]; } u;
            #pragma unroll
            for (int j = 0; j < 8; ++j)
                u.s[j] = f2bf_s(t[kc * 8 + j][col]);
            *(short8*)&out[col * 128 + kcs * 8] = u.v;
        }
    }
}

// ========== GEMM 3-SLOT: 128x256 tile, 2 blocks/CU, counted vmcnt ==========
// BM=128, BN=256, BK=32, 512 thr / 8 waves (2M x 4N), per-wave 64x64,
// acc[4][4] = 64 regs -> <=128 regs/wave -> 16 waves/CU = 2 blocks/CU.
// R4 diagnosis: 1 block/CU means every barrier stalls the whole CU (8 waves
// lockstep); MfmaUtil capped at 27%. With 2 independent blocks the CU
// overlaps block A's LDS/barrier/vmcnt stalls with block B's MFMA (m114).
// LDS 72 KB = 3 slots x (A 8 KB + B 16 KB); rows 64 B, slot = g^((row>>1)&3)
// (same verified-conflict-free involution as R4, rescaled to 64 B rows).
// One phase per K-tile: {4 A + 4 B ds_read_b128; 3 gll16 staging tile t+2
// into slot (t+2)%3; vmcnt(3); BAR; setprio 16 MFMA; BAR}. vmcnt never 0
// in-loop. Ledger (3 loads/wave/phase): at phase t outstanding =
// stage(t+1)+stage(t+2) = 6 -> VM3 retires stage(t+1), read next phase
// (lead ~1 phase ~1500cy > 900cy HBM). Slot t+2 last read at t-1, whose
// reads retired before BAR2(t-1) < stage issue. Tail: VM0 then bare phase.
// Grid 1280 = 160 idx x 8 XCD, panel-major per XCD; heavy (grp0,grp2)
// first, light grp1 (nt=4) packs the tail: ~1.63 effective rounds.
__global__ __launch_bounds__(512, 4) void gemm3s(
    const short* __restrict__ yb, const short* __restrict__ W1yt,
    __hip_bfloat16* __restrict__ Y1b,
    const short* __restrict__ Mt2, const short* __restrict__ W1m2,
    __hip_bfloat16* __restrict__ Mpb,
    const short* __restrict__ W0p, const float* __restrict__ gb0,
    __hip_bfloat16* __restrict__ H0b)
{
    __shared__ __align__(16) char smem[73728];
    const int tid = threadIdx.x;
    const int lane = tid & 63, w = tid >> 6;
    const int l15 = lane & 15, l4 = lane >> 4;
    const int wr = w >> 2, wc = w & 3;

    const int bid = blockIdx.x;
    const int xcd = bid & 7;
    const int idx = bid >> 3;

    int grp, bm, bn, K;
    const short* A; const short* Wt; __hip_bfloat16* C; int ldc;
    if (idx < 64) {
        grp = 0; const int c = idx >> 3, r = idx & 7;
        bm = (xcd * 8 + r) * 128; bn = c * 256;
        A = yb; Wt = W1yt + (long)bn * 1024; K = 1024; C = Y1b; ldc = 2048;
    } else if (idx < 96) {
        int j = idx - 64; const int c = j >> 3, r = j & 7;
        grp = 2; bm = (xcd * 8 + r) * 128; bn = c * 256;
        A = Mt2; Wt = W0p + (long)bn * 1024; K = 1024; C = H0b; ldc = 1024;
    } else {
        int j = idx - 96; const int c = j >> 3, r = j & 7;
        grp = 1; bm = (xcd * 8 + r) * 128; bn = c * 256;
        A = Mt2 + (long)c * (8192L * 128);
        Wt = W1m2 + (long)bn * 128; K = 128; C = Mpb; ldc = 2048;
    }
    const int nt = K >> 5;

    // --- staging maps: unit u -> row u>>2, stored slot u&3 (linear dst),
    //     source k-slot pre-XOR'd with the reader's involution.
    const int rowA = tid >> 2;                 // 0..127
    const int sgA  = (tid & 3) ^ ((rowA >> 1) & 3);
    const int rowB0 = tid >> 2;                // units tid and tid+512
    const int sgB0  = (tid & 3) ^ ((rowB0 >> 1) & 3);
    const int rowB1 = (tid + 512) >> 2;
    const int sgB1  = (tid & 3) ^ ((rowB1 >> 1) & 3);

    auto STAGE = [&](int t, int sl) {
        char* base = smem + sl * 24576;
        const short* asrc;
        if (grp == 2) {
            const int g = t * 4 + sgA;
            asrc = A + (long)(g >> 4) * (8192L * 128)
                     + (long)(bm + rowA) * 128 + (g & 15) * 8;
        } else {
            asrc = A + (long)(bm + rowA) * K + t * 32 + sgA * 8;
        }
        gll16(asrc, base + w * 1024);                       // A: 8 KB
        gll16(Wt + (long)rowB0 * K + t * 32 + sgB0 * 8,
              base + 8192 + w * 1024);                      // B lo 8 KB
        gll16(Wt + (long)rowB1 * K + t * 32 + sgB1 * 8,
              base + 16384 + w * 1024);                     // B hi 8 KB
    };

    f32x4 acc[4][4] = {};
    const int xr = (l4 ^ ((l15 >> 1) & 3)) * 16;
    const int aOff = (wr * 64 + l15) * 64 + xr;
    const int bOff = 8192 + (wc * 64 + l15) * 64 + xr;

    // mode 0: stage(tn)+VM3   1: no stage, VM0   2: bare
    auto PHASE = [&](int sl, int tn, int sl2, int mode) {
        const char* base = smem + sl * 24576;
        short8 a_[4], b_[4];
        #pragma unroll
        for (int m = 0; m < 4; ++m)
            a_[m] = *(const short8*)(base + aOff + m * 1024);
        #pragma unroll
        for (int n = 0; n < 4; ++n)
            b_[n] = *(const short8*)(base + bOff + n * 1024);
        if (mode == 0) { STAGE(tn, sl2); VM3; }
        else if (mode == 1) { VM0; }
        FENCE(); BAR; FENCE();
        __builtin_amdgcn_s_setprio(1);
        #pragma unroll
        for (int m = 0; m < 4; ++m)
            #pragma unroll
            for (int n = 0; n < 4; ++n)
                acc[m][n] = __builtin_amdgcn_mfma_f32_16x16x32_bf16(
                    a_[m], b_[n], acc[m][n], 0, 0, 0);
        __builtin_amdgcn_s_setprio(0);
        FENCE(); BAR; FENCE();
    };

    // prologue: stage tiles 0,1 -> slots 0,1; VM3 lands tile 0
    STAGE(0, 0);
    STAGE(1, 1);
    VM3; FENCE(); BAR; FENCE();

    int sl = 0, sl2 = 2;
    for (int t = 0; t < nt - 2; ++t) {
        PHASE(sl, t + 2, sl2, 0);
        sl = (sl == 2) ? 0 : sl + 1;
        sl2 = (sl2 == 2) ? 0 : sl2 + 1;
    }
    PHASE(sl, 0, 0, 1);                  // drain last stage (VM0)
    sl = (sl == 2) ? 0 : sl + 1;
    PHASE(sl, 0, 0, 2);                  // final tile, no waits

    #pragma unroll
    for (int m = 0; m < 4; ++m) {
        const int row = bm + wr * 64 + m * 16 + l4 * 4;
        #pragma unroll
        for (int n = 0; n < 4; ++n) {
            const int col = bn + wc * 64 + n * 16 + l15;
            const float bv = (grp == 2) ? gb0[col] : 0.f;
            #pragma unroll
            for (int r = 0; r < 4; ++r) {
                float v = acc[m][n][r] + bv;
                if (grp == 2) v = fmaxf(v, 0.f);
                C[(long)(row + r) * ldc + col] = __float2bfloat16(v);
            }
        }
    }
}

// ===== tail_plus: [0,2048) local tail (XCD-swz), [2048,2112) Tg GEMM,
//                  [2112,2176) Ty GEMM (grp3, moved out of the mega GEMM) ===
__global__ __launch_bounds__(256) void tail_plus(
    const __hip_bfloat16* __restrict__ Yp, const __hip_bfloat16* __restrict__ Mq,
    const float* __restrict__ bin, const short* __restrict__ W2s,
    const float* __restrict__ b2, const float* __restrict__ w3,
    const float* __restrict__ b3, double* __restrict__ acc,
    const short* __restrict__ H0b, const short* __restrict__ WgTb,
    __hip_bfloat16* __restrict__ Tgb,
    const short* __restrict__ ybs, const short* __restrict__ l0ws,
    __hip_bfloat16* __restrict__ Tyb)
{
    __shared__ __align__(16) char smem[68096];
    const int bid = blockIdx.x;
    const int tid = threadIdx.x;
    const int lane = tid & 63;
    const int l15 = lane & 15, l4 = lane >> 4;

    if (bid >= 2048) {
        const int sel = bid - 2048;
        const short* Ain = (sel < 64) ? H0b : ybs;
        const short* Bin = (sel < 64) ? WgTb : l0ws;
        __hip_bfloat16* Co = (sel < 64) ? Tgb : Tyb;
        short* As = (short*)smem;
        short* Bs = (short*)(smem + 16384);
        const int w = tid >> 6;
        const int wr = w >> 1, wc = w & 1;
        const int bm = (sel & 63) * 128;
        const int srow = lane >> 3;
        const int gsrc = (lane & 7) ^ srow;

        f32x4 a4[4][4] = {};
        for (int k0 = 0; k0 < 1024; k0 += 64) {
            #pragma unroll
            for (int s = 0; s < 4; ++s) {
                const int rrel = s * 32 + w * 8 + srow;
                gll16(Ain + (long)(bm + rrel) * 1024 + k0 + gsrc * 8,
                      As + (s * 32 + w * 8) * 64);
                gll16(Bin + (long)rrel * 1024 + k0 + gsrc * 8,
                      Bs + (s * 32 + w * 8) * 64);
            }
            __syncthreads();
            #pragma unroll
            for (int st = 0; st < 2; ++st) {
                const int gr = (st * 4 + l4) ^ (l15 & 7);
                short8 a[4], b[4];
                #pragma unroll
                for (int m = 0; m < 4; ++m)
                    a[m] = *(const short8*)&As[(wr * 64 + m * 16 + l15) * 64 + gr * 8];
                #pragma unroll
                for (int n = 0; n < 4; ++n)
                    b[n] = *(const short8*)&Bs[(wc * 64 + n * 16 + l15) * 64 + gr * 8];
                #pragma unroll
                for (int m = 0; m < 4; ++m)
                    #pragma unroll
                    for (int n = 0; n < 4; ++n)
                        a4[m][n] = __builtin_amdgcn_mfma_f32_16x16x32_bf16(a[m], b[n], a4[m][n], 0, 0, 0);
            }
            __syncthreads();
        }
        #pragma unroll
        for (int m = 0; m < 4; ++m) {
            int row = bm + (w >> 1) * 64 + m * 16 + l4 * 4;
            #pragma unroll
            for (int n = 0; n < 4; ++n) {
                int col = (w & 1) * 64 + n * 16 + l15;
                #pragma unroll
                for (int r = 0; r < 4; ++r)
                    Co[(long)(row + r) * 128 + col] = __float2bfloat16(a4[m][n][r]);
            }
        }
        return;
    }

    const int wkid = (bid & 7) * 256 + (bid >> 3);
    const int e = wkid & 15;
    const int b0 = (wkid >> 4) * 64;
    const int cbase = e * 128;
    const int wid = tid >> 6;
    const int side = wid >> 1;
    const int wr = wid & 1;
    const int widthIn = 2048;

    short* h1 = (short*)smem;
    short* Bs = (short*)(smem + 32768);
    float* bins = (float*)(smem + 65536);
    float* b2s  = (float*)(smem + 66048);
    float* w3s  = (float*)(smem + 66560);
    float* red  = (float*)(smem + 67072);

    const short* W2e = W2s + (long)e * 16384;
    #pragma unroll
    for (int l = 0; l < 8; ++l) {
        int cb = (l * 4 + wid) * 64;
        gll16(W2e + (long)(cb + lane) * 8, &Bs[cb * 8]);
    }
    if (tid < 128) {
        bins[tid] = bin[cbase + tid];
        b2s[tid]  = b2[cbase + tid];
        w3s[tid]  = w3[cbase + tid];
    }
    __syncthreads();

    const short* Ys = (const short*)Yp;
    const short* Ms = (const short*)Mq;
    #pragma unroll
    for (int c = 0; c < 4; ++c) {
        int chunk = c * 256 + tid;
        int row = chunk >> 4, kc = chunk & 15;
        short8 yv = *(const short8*)&Ys[(long)(b0 + row) * widthIn + cbase + kc * 8];
        float yf[8];
        #pragma unroll
        for (int j = 0; j < 8; ++j) yf[j] = bf2f(yv[j]) + bins[kc * 8 + j];
        int dst = row * 128 + (kc ^ (row & 7)) * 8;
        #pragma unroll
        for (int s = 0; s < 2; ++s) {
            int rowm = (b0 + row + s) & (B_ROWS - 1);
            short8 mv = *(const short8*)&Ms[(long)rowm * widthIn + cbase + kc * 8];
            union { short8 v; short sh[8]; } o;
            #pragma unroll
            for (int j = 0; j < 8; ++j)
                o.sh[j] = f2bf_s(fmaxf(yf[j] + bf2f(mv[j]), 0.f));
            *(short8*)&h1[s * 8192 + dst] = o.v;
        }
    }
    __syncthreads();

    f32x4 accv[2][8] = {};
    #pragma unroll
    for (int st = 0; st < 4; ++st) {
        short8 a[2], b[8];
        #pragma unroll
        for (int m = 0; m < 2; ++m) {
            int row = wr * 32 + m * 16 + l15;
            int ch = (st * 4 + l4) ^ (row & 7);
            a[m] = *(const short8*)&h1[side * 8192 + row * 128 + ch * 8];
        }
        #pragma unroll
        for (int n = 0; n < 8; ++n) {
            int col = n * 16 + l15;
            int ch = (st * 4 + l4) ^ (col & 7);
            b[n] = *(const short8*)&Bs[col * 128 + ch * 8];
        }
        #pragma unroll
        for (int m = 0; m < 2; ++m)
            #pragma unroll
            for (int n = 0; n < 8; ++n)
                accv[m][n] = __builtin_amdgcn_mfma_f32_16x16x32_bf16(a[m], b[n], accv[m][n], 0, 0, 0);
    }

    float p[2][4] = {};
    #pragma unroll
    for (int m = 0; m < 2; ++m)
        #pragma unroll
        for (int n = 0; n < 8; ++n) {
            int colL = n * 16 + l15;
            float bb = b2s[colL], ww = w3s[colL];
            #pragma unroll
            for (int r = 0; r < 4; ++r) {
                float h2 = fmaxf(accv[m][n][r] + bb, 0.f);
                p[m][r] = fmaf(h2, ww, p[m][r]);
            }
        }
    #pragma unroll
    for (int m = 0; m < 2; ++m)
        #pragma unroll
        for (int r = 0; r < 4; ++r)
            #pragma unroll
            for (int off = 1; off < 16; off <<= 1)
                p[m][r] += __shfl_xor(p[m][r], off, 64);

    float mysum = 0.f;
    if (l15 == 0) {
        float bb = b3[e];
        #pragma unroll
        for (int m = 0; m < 2; ++m)
            #pragma unroll
            for (int r = 0; r < 4; ++r) {
                float s = p[m][r] + bb;
                mysum += softplus_f(side ? s : -s);
            }
    }
    red[tid] = mysum;
    __syncthreads();
    for (int s2 = 128; s2 > 0; s2 >>= 1) {
        if (tid < s2) red[tid] += red[tid + s2];
        __syncthreads();
    }
    if (tid == 0) atomicAdd(acc, (double)red[0]);
}

// ---------- global tail + fused finalize (last-block pattern) --------------
__global__ __launch_bounds__(256) void tail_mfma(
    const __hip_bfloat16* __restrict__ Yp, const __hip_bfloat16* __restrict__ Mq,
    const float* __restrict__ bin,
    const short* __restrict__ W2s,
    const float* __restrict__ b2, const float* __restrict__ w3,
    const float* __restrict__ b3,
    int widthIn, double* __restrict__ acc, int* __restrict__ counter,
    float* __restrict__ out)
{
    const int b0 = blockIdx.x * 64;
    const int e = blockIdx.y;
    const int cbase = e * 128;
    const int tid = threadIdx.x;
    const int lane = tid & 63;
    const int wid = tid >> 6;
    const int side = wid >> 1;
    const int wr = wid & 1;

    __shared__ __align__(16) short h1[2 * 64 * 128];
    __shared__ __align__(16) short Bs[128 * 128];
    __shared__ float bins[128], b2s[128], w3s[128];
    __shared__ float red[256];

    const short* W2e = W2s + (long)e * 16384;
    #pragma unroll
    for (int l = 0; l < 8; ++l) {
        int cb = (l * 4 + wid) * 64;
        gll16(W2e + (long)(cb + lane) * 8, &Bs[cb * 8]);
    }
    if (tid < 128) {
        bins[tid] = bin[cbase + tid];
        b2s[tid]  = b2[cbase + tid];
        w3s[tid]  = w3[cbase + tid];
    }
    __syncthreads();

    const short* Ys = (const short*)Yp;
    const short* Ms = (const short*)Mq;
    #pragma unroll
    for (int c = 0; c < 4; ++c) {
        int chunk = c * 256 + tid;
        int row = chunk >> 4, kc = chunk & 15;
        short8 yv = *(const short8*)&Ys[(long)(b0 + row) * widthIn + cbase + kc * 8];
        float yf[8];
        #pragma unroll
        for (int j = 0; j < 8; ++j) yf[j] = bf2f(yv[j]) + bins[kc * 8 + j];
        int dst = row * 128 + (kc ^ (row & 7)) * 8;
        #pragma unroll
        for (int s = 0; s < 2; ++s) {
            int rowm = (b0 + row + s) & (B_ROWS - 1);
            short8 mv = *(const short8*)&Ms[(long)rowm * widthIn + cbase + kc * 8];
            union { short8 v; short sh[8]; } o;
            #pragma unroll
            for (int j = 0; j < 8; ++j)
                o.sh[j] = f2bf_s(fmaxf(yf[j] + bf2f(mv[j]), 0.f));
            *(short8*)&h1[s * 8192 + dst] = o.v;
        }
    }
    __syncthreads();

    const int l15 = lane & 15, l4 = lane >> 4;
    f32x4 accv[2][8] = {};
    #pragma unroll
    for (int st = 0; st < 4; ++st) {
        short8 a[2], b[8];
        #pragma unroll
        for (int m = 0; m < 2; ++m) {
            int row = wr * 32 + m * 16 + l15;
            int ch = (st * 4 + l4) ^ (row & 7);
            a[m] = *(const short8*)&h1[side * 8192 + row * 128 + ch * 8];
        }
        #pragma unroll
        for (int n = 0; n < 8; ++n) {
            int col = n * 16 + l15;
            int ch = (st * 4 + l4) ^ (col & 7);
            b[n] = *(const short8*)&Bs[col * 128 + ch * 8];
        }
        #pragma unroll
        for (int m = 0; m < 2; ++m)
            #pragma unroll
            for (int n = 0; n < 8; ++n)
                accv[m][n] = __builtin_amdgcn_mfma_f32_16x16x32_bf16(a[m], b[n], accv[m][n], 0, 0, 0);
    }

    float p[2][4] = {};
    #pragma unroll
    for (int m = 0; m < 2; ++m)
        #pragma unroll
        for (int n = 0; n < 8; ++n) {
            int colL = n * 16 + l15;
            float bb = b2s[colL], ww = w3s[colL];
            #pragma unroll
            for (int r = 0; r < 4; ++r) {
                float h2 = fmaxf(accv[m][n][r] + bb, 0.f);
                p[m][r] = fmaf(h2, ww, p[m][r]);
            }
        }
    #pragma unroll
    for (int m = 0; m < 2; ++m)
        #pragma unroll
        for (int r = 0; r < 4; ++r)
            #pragma unroll
            for (int off = 1; off < 16; off <<= 1)
                p[m][r] += __shfl_xor(p[m][r], off, 64);

    float mysum = 0.f;
    if (l15 == 0) {
        float bb = b3[e];
        #pragma unroll
        for (int m = 0; m < 2; ++m)
            #pragma unroll
            for (int r = 0; r < 4; ++r) {
                float s = p[m][r] + bb;
                mysum += softplus_f(side ? s : -s);
            }
    }
    red[tid] = mysum;
    __syncthreads();
    for (int s2 = 128; s2 > 0; s2 >>= 1) {
        if (tid < s2) red[tid] += red[tid + s2];
        __syncthreads();
    }
    if (tid == 0) {
        atomicAdd(acc + 1, (double)red[0]);
        __threadfence();
        int old = atomicAdd(counter, 1);
        if (old == (int)(gridDim.x * gridDim.y) - 1) {
            double a0 = atomicAdd(acc + 0, 0.0);
            double a1 = atomicAdd(acc + 1, 0.0);
            out[0] = (float)(a0 / (8192.0 * 16.0) + 0.5 * a1 / 8192.0);
        }
    }
}

extern "C" void kernel_launch(void* const* d_in, const int* in_sizes, int n_in,
                              void* d_out, int out_size, void* d_ws, size_t ws_size,
                              hipStream_t stream)
{
    const float* y   = (const float*)d_in[0];
    const float* M   = (const float*)d_in[1];
    const float* gw0 = (const float*)d_in[2];
    const float* gb0 = (const float*)d_in[3];
    const float* gw1 = (const float*)d_in[4];
    const float* gb1 = (const float*)d_in[5];
    const float* l0w = (const float*)d_in[6];
    const float* l0b = (const float*)d_in[7];
    const float* l1w = (const float*)d_in[8];
    const float* l1b = (const float*)d_in[9];
    const float* l2w = (const float*)d_in[10];
    const float* l2b = (const float*)d_in[11];
    const float* lW1 = (const float*)d_in[12];
    const float* lb1 = (const float*)d_in[13];
    const float* lW2 = (const float*)d_in[14];
    const float* lb2 = (const float*)d_in[15];
    const float* lW3 = (const float*)d_in[16];
    const float* lb3 = (const float*)d_in[17];

    // ---- workspace layout (~127 MB) ----
    char* w = (char*)d_ws;
    double* acc = (double*)w;
    int* counter = (int*)(w + 16);
    float* bing = (float*)(w + 256);
    const size_t MB = 1u << 20;
    __hip_bfloat16* Y1b  = (__hip_bfloat16*)(w + 4096);             // 32 MB
    __hip_bfloat16* Mpb  = (__hip_bfloat16*)(w + 4096 + 32 * MB);   // 32 MB
    __hip_bfloat16* H0b  = (__hip_bfloat16*)(w + 4096 + 64 * MB);   // 16 MB
    short*          Mt2  = (short*)(w + 4096 + 80 * MB);            // 16 MB
    __hip_bfloat16* yb   = (__hip_bfloat16*)(w + 4096 + 96 * MB);   // 16 MB
    __hip_bfloat16* W1yt = (__hip_bfloat16*)(w + 4096 + 112 * MB);  // 4 MB
    __hip_bfloat16* W0p  = (__hip_bfloat16*)(w + 4096 + 118 * MB);  // 2 MB
    __hip_bfloat16* l0wyt = (__hip_bfloat16*)(w + 4096 + 120 * MB); // 256 KB
    short* W2sb = (short*)(w + 4096 + 120 * MB + 512 * 1024);       // 512 KB
    short* L1ws = (short*)(w + 4096 + 121 * MB);                    // 32 KB
    __hip_bfloat16* WgTb = (__hip_bfloat16*)(w + 4096 + 121 * MB + 512 * 1024); // 256 KB
    short* W1m2 = (short*)(w + 4096 + 122 * MB);                    // 512 KB
    __hip_bfloat16* Tyb = (__hip_bfloat16*)(w + 4096 + 123 * MB);   // 2 MB
    __hip_bfloat16* Tgb = (__hip_bfloat16*)(w + 4096 + 125 * MB);   // 2 MB

    dim3 blk(256);

    prep_all<<<dim3(10074), blk, 0, stream>>>(
        y, M, lW1, gw0, l0w, gb1, l0b, lW2, l1w, gw1,
        yb, Mt2, W1yt, W1m2, W0p, l0wyt, bing, W2sb, L1ws, WgTb,
        acc, counter);

    gemm3s<<<dim3(1280), dim3(512), 0, stream>>>(
        (const short*)yb, (const short*)W1yt, Y1b,
        Mt2, W1m2, Mpb,
        (const short*)W0p, gb0, H0b);

    tail_plus<<<dim3(2176), blk, 0, stream>>>(
        Y1b, Mpb, lb1, W2sb, lb2, lW3, lb3, acc,
        (const short*)H0b, (const short*)WgTb, Tgb,
        (const short*)yb, (const short*)l0wyt, Tyb);

    tail_mfma<<<dim3(128, 1), blk, 0, stream>>>(
        Tyb, Tgb, bing, L1ws, l1b, l2w, l2b, 128, acc, counter,
        (float*)d_out);
}